// Round 15
// baseline (343.129 us; speedup 1.0000x reference)
//
#include <hip/hip_runtime.h>
#include <math.h>

#define B_   16
#define CC   256
#define NN   4096   // 64*64
#define MM   256    // 16*16
#define NH   8
#define HD   32
// scale * log2(e): softmax done in base-2
#define QSCALE (0.17677669529663687f * 1.4426950408889634f)

typedef float fx4 __attribute__((ext_vector_type(4)));
typedef short sx4 __attribute__((ext_vector_type(4)));
typedef short sx8 __attribute__((ext_vector_type(8)));

__device__ inline short f2bf(float f) {
  unsigned u = __builtin_bit_cast(unsigned, f);
  u += 0x7FFFu + ((u >> 16) & 1u);   // RNE
  return (short)(u >> 16);
}
__device__ inline float bf2f(short s) {
  unsigned u = ((unsigned)(unsigned short)s) << 16;
  return __builtin_bit_cast(float, u);
}
__device__ inline unsigned cvtpk_bf16(float a, float b) {
  unsigned r;
  asm("v_cvt_pk_bf16_f32 %0, %1, %2" : "=v"(r) : "v"(a), "v"(b));
  return r;
}
__device__ inline float fexp2(float x) {
#if __has_builtin(__builtin_amdgcn_exp2f)
  return __builtin_amdgcn_exp2f(x);
#else
  return exp2f(x);
#endif
}
__device__ inline float frcp(float x) {
#if __has_builtin(__builtin_amdgcn_rcpf)
  return __builtin_amdgcn_rcpf(x);
#else
  return 1.0f / x;
#endif
}

// ---------- weight transpose + bf16 split ----------
// KT=false: W[K][N] f32 -> Th/Tl[N][K] bf16 (row-major-T).
// KT=true:  W[K][N] f32 -> Th/Tl[K/32][N][32] bf16 (k-tile-major).
template<bool KT>
__global__ __launch_bounds__(256) void wsplit_kernel(
    const float* __restrict__ W, short* __restrict__ Th, short* __restrict__ Tl,
    int K, int N)
{
  __shared__ float Tile[64][65];
  const int t = threadIdx.x;
  const int k0 = blockIdx.y << 6, n0 = blockIdx.x << 6;
#pragma unroll
  for (int i = 0; i < 4; ++i) {
    int idx = t + (i << 8);
    int k = idx >> 4, n4 = (idx & 15) << 2;
    float4 v = *(const float4*)&W[(size_t)(k0 + k) * N + n0 + n4];
    Tile[k][n4 + 0] = v.x; Tile[k][n4 + 1] = v.y;
    Tile[k][n4 + 2] = v.z; Tile[k][n4 + 3] = v.w;
  }
  __syncthreads();
#pragma unroll
  for (int i = 0; i < 4; ++i) {
    int idx = t + (i << 8);
    int n = idx >> 4, k4 = (idx & 15) << 2;
    sx4 h, lo;
#pragma unroll
    for (int j = 0; j < 4; ++j) {
      float v = Tile[k4 + j][n];
      short hh = f2bf(v);
      h[j] = hh;
      lo[j] = f2bf(v - bf2f(hh));
    }
    int kk = k0 + k4, nn = n0 + n;
    size_t dst;
    if constexpr (KT)
      dst = ((size_t)(kk >> 5) * N << 5) + ((size_t)nn << 5) + (kk & 31);
    else
      dst = (size_t)nn * K + kk;
    *(sx4*)&Th[dst] = h;
    *(sx4*)&Tl[dst] = lo;
  }
}

// ---------- wide-N split-bf16 GEMM v2: zero LDS, B-frags straight from k-tiled global ----------
// Block = 64 rows x 256 cols, 4 waves. For fixed j, the 64 lanes' 16B reads span one
// contiguous 1KB line (L1-hot, shared by all 4 waves). No barriers.
// AM: 0 = A f32 row-major; 2 = A pre-split bf16 head-major [b*8+h][n][32].
// EP: 0 = f32 C + bias; 3 = q bf16 prescaled -> [b*8+h][n][32].
template<int AM, int EP>
__global__ __launch_bounds__(256) void gemm_wide_kernel(
    const void* __restrict__ Av, const short* __restrict__ Alo,
    const short* __restrict__ Bth, const short* __restrict__ Btl,
    const float* __restrict__ bias, float* __restrict__ C,
    short* __restrict__ qout, int M, int K)
{
  const int t = threadIdx.x;
  const int bm = blockIdx.x << 6;
  const int w = t >> 6, l = t & 63, g = l >> 4, c = l & 15;
  const int g8 = g << 3;
  const int arow = bm + (w << 4) + c;

  float4 pa0, pa1; sx8 pah, pal;
  auto LOADA = [&](int k0) {
    if constexpr (AM == 2) {
      size_t idx = ((size_t)(arow >> 12) << 20) + ((size_t)(k0 >> 5) << 17)
                 + ((size_t)(arow & 4095) << 5) + g8;
      pah = *(const sx8*)&((const short*)Av)[idx];
      pal = *(const sx8*)&Alo[idx];
    } else {
      const float* ap = (const float*)Av + (size_t)arow * K + k0 + g8;
      pa0 = *(const float4*)ap;
      pa1 = *(const float4*)(ap + 4);
    }
  };

  fx4 acc[16];
#pragma unroll
  for (int j = 0; j < 16; ++j) acc[j] = fx4{0.f, 0.f, 0.f, 0.f};

  LOADA(0);
  for (int k0 = 0; k0 < K; k0 += 32) {
    sx8 ah, al;
    if constexpr (AM == 2) { ah = pah; al = pal; }
    else {
      ah[0]=f2bf(pa0.x); al[0]=f2bf(pa0.x-bf2f(ah[0]));
      ah[1]=f2bf(pa0.y); al[1]=f2bf(pa0.y-bf2f(ah[1]));
      ah[2]=f2bf(pa0.z); al[2]=f2bf(pa0.z-bf2f(ah[2]));
      ah[3]=f2bf(pa0.w); al[3]=f2bf(pa0.w-bf2f(ah[3]));
      ah[4]=f2bf(pa1.x); al[4]=f2bf(pa1.x-bf2f(ah[4]));
      ah[5]=f2bf(pa1.y); al[5]=f2bf(pa1.y-bf2f(ah[5]));
      ah[6]=f2bf(pa1.z); al[6]=f2bf(pa1.z-bf2f(ah[6]));
      ah[7]=f2bf(pa1.w); al[7]=f2bf(pa1.w-bf2f(ah[7]));
    }
    if (k0 + 32 < K) LOADA(k0 + 32);
    const short* bh_base = Bth + (((size_t)(k0 >> 5)) << 13) + c * 32 + g8;
    const short* bl_base = Btl + (((size_t)(k0 >> 5)) << 13) + c * 32 + g8;
#pragma unroll
    for (int j = 0; j < 16; ++j) {
      sx8 bh = *(const sx8*)&bh_base[j << 9];
      sx8 bl = *(const sx8*)&bl_base[j << 9];
      acc[j] = __builtin_amdgcn_mfma_f32_16x16x32_bf16(ah, bh, acc[j], 0, 0, 0);
      acc[j] = __builtin_amdgcn_mfma_f32_16x16x32_bf16(al, bh, acc[j], 0, 0, 0);
      acc[j] = __builtin_amdgcn_mfma_f32_16x16x32_bf16(ah, bl, acc[j], 0, 0, 0);
    }
  }

  const int orow = bm + (w << 4) + (g << 2);
#pragma unroll
  for (int j = 0; j < 16; ++j) {
    const int col = (j << 4) + c;
    const float bb = bias[col];
    if constexpr (EP == 0) {
#pragma unroll
      for (int i = 0; i < 4; ++i)
        C[(size_t)(orow + i) * 256 + col] = acc[j][i] + bb;
    } else {  // EP == 3: q bf16 prescaled head-major
      const int h = col >> 5, d = col & 31;
#pragma unroll
      for (int i = 0; i < 4; ++i) {
        int r = orow + i;
        qout[((size_t)(((r >> 12) << 3) + h) * 4096 + (r & 4095)) * 32 + d]
            = f2bf((acc[j][i] + bb) * QSCALE);
      }
    }
  }
}

// ---------- classic split-bf16 GEMM (f32 A): conv partials + kv ----------
template<bool GATHER, int EPI>
__global__ __launch_bounds__(256) void gemm_split_kernel(
    const float* __restrict__ A, const short* __restrict__ Bth,
    const short* __restrict__ Btl, const float* __restrict__ bias,
    float* __restrict__ C, short* __restrict__ kout, short* __restrict__ vout,
    int M, int N, int K)
{
  __shared__ short Ah[64][40], Al[64][40], Bh[64][40], Bl[64][40];
  const int t = threadIdx.x;
  const int bm = blockIdx.y << 6, bn = blockIdx.x << 6;
  const int ar = t >> 2, ak = (t & 3) << 3;
  const int bc = t >> 2, bk = (t & 3) << 3;

  int sp_base = 0;
  if (GATHER) {
    int gr = bm + ar;
    int b = gr >> 8, mm2 = gr & 255;
    int oh = mm2 >> 4, ow = mm2 & 15;
    sp_base = b * 4096 + oh * 256 + ow * 4;
  }
  const size_t brow = (size_t)(bn + bc) * K;

  const int KS = K / gridDim.z;
  const int kbeg = blockIdx.z * KS, kend = kbeg + KS;

  float4 pa0, pa1; sx8 pbh, pbl;
  auto LOADG = [&](int k0) {
    int k = k0 + ak;
    const float* ap;
    if (GATHER) {
      int pos = k >> 8, ci = k & 255;
      ap = &A[(size_t)(sp_base + ((pos >> 2) << 6) + (pos & 3)) * 256 + ci];
    } else {
      ap = &A[(size_t)(bm + ar) * K + k];
    }
    pa0 = *(const float4*)ap;
    pa1 = *(const float4*)(ap + 4);
    pbh = *(const sx8*)&Bth[brow + k0 + bk];
    pbl = *(const sx8*)&Btl[brow + k0 + bk];
  };

  const int w = t >> 6, l = t & 63, g = l >> 4, c = l & 15;
  const int wr = w >> 1, wc = w & 1;
  const int ra0 = (wr << 5) + c, ra1 = ra0 + 16;
  const int cb0 = (wc << 5) + c, cb1 = cb0 + 16;
  const int g8 = g << 3;

  fx4 acc00 = {0.f,0.f,0.f,0.f}, acc01 = acc00, acc10 = acc00, acc11 = acc00;

  LOADG(kbeg);
  for (int k0 = kbeg; k0 < kend; k0 += 32) {
    sx4 AH0, AL0, AH1, AL1;
    AH0[0]=f2bf(pa0.x); AL0[0]=f2bf(pa0.x-bf2f(AH0[0]));
    AH0[1]=f2bf(pa0.y); AL0[1]=f2bf(pa0.y-bf2f(AH0[1]));
    AH0[2]=f2bf(pa0.z); AL0[2]=f2bf(pa0.z-bf2f(AH0[2]));
    AH0[3]=f2bf(pa0.w); AL0[3]=f2bf(pa0.w-bf2f(AH0[3]));
    AH1[0]=f2bf(pa1.x); AL1[0]=f2bf(pa1.x-bf2f(AH1[0]));
    AH1[1]=f2bf(pa1.y); AL1[1]=f2bf(pa1.y-bf2f(AH1[1]));
    AH1[2]=f2bf(pa1.z); AL1[2]=f2bf(pa1.z-bf2f(AH1[2]));
    AH1[3]=f2bf(pa1.w); AL1[3]=f2bf(pa1.w-bf2f(AH1[3]));
    *(sx4*)&Ah[ar][ak]     = AH0;  *(sx4*)&Ah[ar][ak + 4] = AH1;
    *(sx4*)&Al[ar][ak]     = AL0;  *(sx4*)&Al[ar][ak + 4] = AL1;
    *(sx8*)&Bh[bc][bk] = pbh;      *(sx8*)&Bl[bc][bk] = pbl;
    __syncthreads();
    if (k0 + 32 < kend) LOADG(k0 + 32);

    sx8 a0h = *(const sx8*)&Ah[ra0][g8];
    sx8 a0l = *(const sx8*)&Al[ra0][g8];
    sx8 a1h = *(const sx8*)&Ah[ra1][g8];
    sx8 a1l = *(const sx8*)&Al[ra1][g8];
    sx8 b0h = *(const sx8*)&Bh[cb0][g8];
    sx8 b0l = *(const sx8*)&Bl[cb0][g8];
    sx8 b1h = *(const sx8*)&Bh[cb1][g8];
    sx8 b1l = *(const sx8*)&Bl[cb1][g8];

    acc00 = __builtin_amdgcn_mfma_f32_16x16x32_bf16(a0h, b0h, acc00, 0, 0, 0);
    acc01 = __builtin_amdgcn_mfma_f32_16x16x32_bf16(a0h, b1h, acc01, 0, 0, 0);
    acc10 = __builtin_amdgcn_mfma_f32_16x16x32_bf16(a1h, b0h, acc10, 0, 0, 0);
    acc11 = __builtin_amdgcn_mfma_f32_16x16x32_bf16(a1h, b1h, acc11, 0, 0, 0);
    acc00 = __builtin_amdgcn_mfma_f32_16x16x32_bf16(a0l, b0h, acc00, 0, 0, 0);
    acc01 = __builtin_amdgcn_mfma_f32_16x16x32_bf16(a0l, b1h, acc01, 0, 0, 0);
    acc10 = __builtin_amdgcn_mfma_f32_16x16x32_bf16(a1l, b0h, acc10, 0, 0, 0);
    acc11 = __builtin_amdgcn_mfma_f32_16x16x32_bf16(a1l, b1h, acc11, 0, 0, 0);
    acc00 = __builtin_amdgcn_mfma_f32_16x16x32_bf16(a0h, b0l, acc00, 0, 0, 0);
    acc01 = __builtin_amdgcn_mfma_f32_16x16x32_bf16(a0h, b1l, acc01, 0, 0, 0);
    acc10 = __builtin_amdgcn_mfma_f32_16x16x32_bf16(a1h, b0l, acc10, 0, 0, 0);
    acc11 = __builtin_amdgcn_mfma_f32_16x16x32_bf16(a1h, b1l, acc11, 0, 0, 0);
    __syncthreads();
  }

  const int col0 = bn + (wc << 5);
  const int row0 = bm + (wr << 5) + (g << 2);
  if constexpr (EPI == 1) {
    float* Cz = C + (size_t)blockIdx.z * M * N;
#pragma unroll
    for (int i = 0; i < 4; ++i) {
      Cz[(size_t)(row0 + i) * N + col0 + c]           = acc00[i];
      Cz[(size_t)(row0 + i) * N + col0 + 16 + c]      = acc01[i];
      Cz[(size_t)(row0 + 16 + i) * N + col0 + c]      = acc10[i];
      Cz[(size_t)(row0 + 16 + i) * N + col0 + 16 + c] = acc11[i];
    }
  } else {  // EPI == 2: kv emit -> K/V [b*8+h][m][32] bf16
    const float b0 = bias[col0 + c], b1 = bias[col0 + 16 + c];
    auto emit = [&](int row, int n, float v) {
      int b = row >> 8, m = row & 255;
      short* dst = (n < 256) ? kout : vout;
      int nn = n & 255;
      int h = nn >> 5, d = nn & 31;
      dst[(size_t)(((b << 3) + h) * 256 + m) * 32 + d] = f2bf(v);
    };
#pragma unroll
    for (int i = 0; i < 4; ++i) {
      emit(row0 + i,      col0 + c,      acc00[i] + b0);
      emit(row0 + i,      col0 + 16 + c, acc01[i] + b1);
      emit(row0 + 16 + i, col0 + c,      acc10[i] + b0);
      emit(row0 + 16 + i, col0 + 16 + c, acc11[i] + b1);
    }
  }
}

// -------- fused K-split reduce (8 parts) + bias + LayerNorm: xs row per block --------
__global__ __launch_bounds__(256) void ln_reduce_kernel(
    const float* __restrict__ parts, const float* __restrict__ bias,
    const float* __restrict__ g, const float* __restrict__ bta,
    float* __restrict__ xs)
{
  const int row = blockIdx.x, t = threadIdx.x;
  const size_t MN = (size_t)4096 * 256;
  const size_t off = (size_t)row * CC + t;
  float v = bias[t];
#pragma unroll
  for (int p = 0; p < 8; ++p) v += parts[p * MN + off];
  float s = v, s2 = v * v;
#pragma unroll
  for (int offs = 32; offs; offs >>= 1) {
    s  += __shfl_xor(s,  offs, 64);
    s2 += __shfl_xor(s2, offs, 64);
  }
  __shared__ float red[8];
  const int w = t >> 6, lane = t & 63;
  if (lane == 0) { red[w] = s; red[4 + w] = s2; }
  __syncthreads();
  float ts  = red[0] + red[1] + red[2] + red[3];
  float ts2 = red[4] + red[5] + red[6] + red[7];
  float mu  = ts * (1.0f / 256.0f);
  float var = ts2 * (1.0f / 256.0f) - mu * mu;
  float o = (v - mu) * rsqrtf(var + 1e-6f) * g[t] + bta[t];
  xs[off] = o;
}

// ---------------- MFMA attention v4: k-permuted P/V, cvt_pk packed P stores ----------------
__global__ __launch_bounds__(256, 3) void attn_mfma4_kernel(
    short* __restrict__ qob, short* __restrict__ olo,
    const short* __restrict__ kbf, const short* __restrict__ vbf)
{
  __shared__ short Vt[32 * 264];       // V^T [d][m'], stride 264
  __shared__ short Ps[4 * 16 * 264];   // per-wave P [16 rows][m'], stride 264

  const int tid = threadIdx.x;
  const int bid = blockIdx.x;
  const int nt = bid & 63, h = (bid >> 6) & 7, b = bid >> 9;
  const int n0 = nt << 6;
  const int bh = (b << 3) + h;
  const short* kb = kbf + (size_t)bh * 8192;
  const short* vb = vbf + (size_t)bh * 8192;

  // ---- stage V^T with m-permute ----
  {
    const int msrc = ((tid & 15) << 4) | (tid >> 4);
    sx8 v0 = *(const sx8*)&vb[msrc * 32 + 0];
    sx8 v1 = *(const sx8*)&vb[msrc * 32 + 8];
    sx8 v2 = *(const sx8*)&vb[msrc * 32 + 16];
    sx8 v3 = *(const sx8*)&vb[msrc * 32 + 24];
#pragma unroll
    for (int e = 0; e < 8; ++e) {
      Vt[(e)      * 264 + tid] = v0[e];
      Vt[(8 + e)  * 264 + tid] = v1[e];
      Vt[(16 + e) * 264 + tid] = v2[e];
      Vt[(24 + e) * 264 + tid] = v3[e];
    }
  }

  const int w = tid >> 6, l = tid & 63;
  const int g = l >> 4, c = l & 15;

  // ---- Q A-fragment: direct bf16 load ----
  sx8 aq = *(const sx8*)&qob[((size_t)bh * 4096 + n0 + w * 16 + c) * 32 + (g << 3)];

  // ---- S = Q K^T ----
  fx4 acc[16];
#pragma unroll
  for (int j = 0; j < 16; ++j) {
    sx8 bk = *(const sx8*)&kb[(j * 16 + c) * 32 + (g << 3)];
    fx4 z = {0.f, 0.f, 0.f, 0.f};
    acc[j] = __builtin_amdgcn_mfma_f32_16x16x32_bf16(aq, bk, z, 0, 0, 0);
  }

  // ---- in-register softmax ----
  float mx[4], sm[4];
#pragma unroll
  for (int i = 0; i < 4; ++i) {
    float m0 = acc[0][i];
#pragma unroll
    for (int j = 1; j < 16; ++j) m0 = fmaxf(m0, acc[j][i]);
    m0 = fmaxf(m0, __shfl_xor(m0, 1, 64));
    m0 = fmaxf(m0, __shfl_xor(m0, 2, 64));
    m0 = fmaxf(m0, __shfl_xor(m0, 4, 64));
    m0 = fmaxf(m0, __shfl_xor(m0, 8, 64));
    mx[i] = m0;
  }
#pragma unroll
  for (int i = 0; i < 4; ++i) {
    float s0 = 0.f;
#pragma unroll
    for (int j = 0; j < 16; ++j) {
      float p = fexp2(acc[j][i] - mx[i]);
      acc[j][i] = p; s0 += p;
    }
    s0 += __shfl_xor(s0, 1, 64);
    s0 += __shfl_xor(s0, 2, 64);
    s0 += __shfl_xor(s0, 4, 64);
    s0 += __shfl_xor(s0, 8, 64);
    sm[i] = s0;
  }

  // ---- P -> LDS: contiguous per thread; 8 cvt_pk + 2 b128 per row ----
  const int pbase = (w << 4) * 264;
#pragma unroll
  for (int i = 0; i < 4; ++i) {
    unsigned p0 = cvtpk_bf16(acc[0][i],  acc[1][i]);
    unsigned p1 = cvtpk_bf16(acc[2][i],  acc[3][i]);
    unsigned p2 = cvtpk_bf16(acc[4][i],  acc[5][i]);
    unsigned p3 = cvtpk_bf16(acc[6][i],  acc[7][i]);
    unsigned p4 = cvtpk_bf16(acc[8][i],  acc[9][i]);
    unsigned p5 = cvtpk_bf16(acc[10][i], acc[11][i]);
    unsigned p6 = cvtpk_bf16(acc[12][i], acc[13][i]);
    unsigned p7 = cvtpk_bf16(acc[14][i], acc[15][i]);
    unsigned* dst = (unsigned*)&Ps[pbase + ((g << 2) + i) * 264 + (c << 4)];
    uint4 lo4; lo4.x = p0; lo4.y = p1; lo4.z = p2; lo4.w = p3;
    uint4 hi4; hi4.x = p4; hi4.y = p5; hi4.z = p6; hi4.w = p7;
    *(uint4*)dst       = lo4;
    *(uint4*)(dst + 4) = hi4;
  }

  __syncthreads();

  // ---- O = P V over permuted k ----
  fx4 o0 = {0.f,0.f,0.f,0.f}, o1 = {0.f,0.f,0.f,0.f};
#pragma unroll
  for (int s = 0; s < 8; ++s) {
    sx8 ap  = *(const sx8*)&Ps[pbase + c * 264 + (s << 5) + (g << 3)];
    sx8 bv0 = *(const sx8*)&Vt[(c)      * 264 + (s << 5) + (g << 3)];
    sx8 bv1 = *(const sx8*)&Vt[(16 + c) * 264 + (s << 5) + (g << 3)];
    o0 = __builtin_amdgcn_mfma_f32_16x16x32_bf16(ap, bv0, o0, 0, 0, 0);
    o1 = __builtin_amdgcn_mfma_f32_16x16x32_bf16(ap, bv1, o1, 0, 0, 0);
  }

  // ---- normalize, split to bf16 hi/lo, write [b*8+h][n][32] ----
#pragma unroll
  for (int i = 0; i < 4; ++i) {
    float inv = frcp(sm[i]);
    int n = n0 + w * 16 + (g << 2) + i;
    size_t base = ((size_t)bh * 4096 + n) * 32;
    float v0 = o0[i] * inv, v1 = o1[i] * inv;
    short h0 = f2bf(v0), h1 = f2bf(v1);
    qob[base + c]      = h0;  olo[base + c]      = f2bf(v0 - bf2f(h0));
    qob[base + 16 + c] = h1;  olo[base + 16 + c] = f2bf(v1 - bf2f(h1));
  }
}

extern "C" void kernel_launch(void* const* d_in, const int* in_sizes, int n_in,
                              void* d_out, int out_size, void* d_ws, size_t ws_size,
                              hipStream_t stream) {
  const float* x      = (const float*)d_in[0];
  const float* q_w    = (const float*)d_in[1];
  const float* q_b    = (const float*)d_in[2];
  const float* kv_w   = (const float*)d_in[3];
  const float* kv_b   = (const float*)d_in[4];
  const float* sr_w   = (const float*)d_in[5];
  const float* sr_b   = (const float*)d_in[6];
  const float* norm_g = (const float*)d_in[7];
  const float* norm_b = (const float*)d_in[8];
  const float* proj_w = (const float*)d_in[9];
  const float* proj_b = (const float*)d_in[10];
  float* out = (float*)d_out;

  // workspace
  float* xsbuf = (float*)d_ws;                     // 4 MB
  short* qbf   = (short*)(xsbuf + 1048576);        // 32 MB: q bf16, then O-hi
  short* olo   = qbf + 16777216;                   // 32 MB: O-lo
  short* kbf   = olo + 16777216;                   // 4 MB
  short* vbf   = kbf + 2097152;                    // 4 MB
  short* qwt_h  = vbf + 2097152;
  short* qwt_l  = qwt_h + 65536;
  short* kvwt_h = qwt_l + 65536;
  short* kvwt_l = kvwt_h + 131072;
  short* pwt_h  = kvwt_l + 131072;
  short* pwt_l  = pwt_h + 65536;
  short* swt_h  = pwt_l + 65536;
  short* swt_l  = swt_h + 1048576;
  // d_out (64 MB) as early scratch: conv K-split partials (8 x 4 MB = 32 MB)
  float* partf = out;

  dim3 blk(256);

  wsplit_kernel<true><<<dim3(CC/64, CC/64), blk, 0, stream>>>(q_w, qwt_h, qwt_l, CC, CC);
  wsplit_kernel<false><<<dim3(2*CC/64, CC/64), blk, 0, stream>>>(kv_w, kvwt_h, kvwt_l, CC, 2*CC);
  wsplit_kernel<true><<<dim3(CC/64, CC/64), blk, 0, stream>>>(proj_w, pwt_h, pwt_l, CC, CC);
  wsplit_kernel<false><<<dim3(CC/64, 4096/64), blk, 0, stream>>>(sr_w, swt_h, swt_l, 4096, CC);

  // 1) q = x @ q_w + q_b -> bf16 prescaled [b*8+h][n][32]
  gemm_wide_kernel<0,3><<<dim3((B_*NN)/64), blk, 0, stream>>>(
      x, nullptr, qwt_h, qwt_l, q_b, nullptr, qbf, B_*NN, CC);

  // 2) conv (gathered GEMM, K=4096), K-split x8 -> f32 partials in d_out
  gemm_split_kernel<true,1><<<dim3(CC/64, (B_*MM)/64, 8), blk, 0, stream>>>(
      x, swt_h, swt_l, sr_b, partf, nullptr, nullptr, B_*MM, CC, 4096);

  // 3) fused reduce (8 parts) + bias + LayerNorm
  ln_reduce_kernel<<<B_ * MM, blk, 0, stream>>>(partf, sr_b, norm_g, norm_b, xsbuf);

  // 4) kv = xs @ kv_w + kv_b -> bf16 K/V [b*8+h][m][32]
  gemm_split_kernel<false,2><<<dim3((2*CC)/64, (B_*MM)/64, 1), blk, 0, stream>>>(
      xsbuf, kvwt_h, kvwt_l, kv_b, nullptr, kbf, vbf, B_*MM, 2*CC, CC);

  // 5) attention: reads qbf, writes O-hi over qbf + O-lo
  attn_mfma4_kernel<<<B_ * NH * (NN / 64), blk, 0, stream>>>(qbf, olo, kbf, vbf);

  // 6) out = O @ proj_w + proj_b
  gemm_wide_kernel<2,0><<<dim3((B_*NN)/64), blk, 0, stream>>>(
      qbf, olo, pwt_h, pwt_l, proj_b, out, nullptr, B_*NN, CC);
}

// Round 16
// 236.731 us; speedup vs baseline: 1.4494x; 1.4494x over previous
//
#include <hip/hip_runtime.h>
#include <math.h>

#define B_   16
#define CC   256
#define NN   4096   // 64*64
#define MM   256    // 16*16
#define NH   8
#define HD   32
// scale * log2(e): softmax done in base-2
#define QSCALE (0.17677669529663687f * 1.4426950408889634f)

typedef float fx4 __attribute__((ext_vector_type(4)));
typedef short sx4 __attribute__((ext_vector_type(4)));
typedef short sx8 __attribute__((ext_vector_type(8)));

__device__ inline short f2bf(float f) {
  unsigned u = __builtin_bit_cast(unsigned, f);
  u += 0x7FFFu + ((u >> 16) & 1u);   // RNE
  return (short)(u >> 16);
}
__device__ inline float bf2f(short s) {
  unsigned u = ((unsigned)(unsigned short)s) << 16;
  return __builtin_bit_cast(float, u);
}
__device__ inline unsigned cvtpk_bf16(float a, float b) {
  unsigned r;
  asm("v_cvt_pk_bf16_f32 %0, %1, %2" : "=v"(r) : "v"(a), "v"(b));
  return r;
}
__device__ inline float fexp2(float x) {
#if __has_builtin(__builtin_amdgcn_exp2f)
  return __builtin_amdgcn_exp2f(x);
#else
  return exp2f(x);
#endif
}
__device__ inline float frcp(float x) {
#if __has_builtin(__builtin_amdgcn_rcpf)
  return __builtin_amdgcn_rcpf(x);
#else
  return 1.0f / x;
#endif
}

// ---------- weight transpose + bf16 split ----------
// KT=false: W[K][N] f32 -> Th/Tl[N][K] bf16 (row-major-T).
// KT=true:  W[K][N] f32 -> Th/Tl[K/32][N][32] bf16 (k-tile-major, coalesced loads).
template<bool KT>
__global__ __launch_bounds__(256) void wsplit_kernel(
    const float* __restrict__ W, short* __restrict__ Th, short* __restrict__ Tl,
    int K, int N)
{
  __shared__ float Tile[64][65];
  const int t = threadIdx.x;
  const int k0 = blockIdx.y << 6, n0 = blockIdx.x << 6;
#pragma unroll
  for (int i = 0; i < 4; ++i) {
    int idx = t + (i << 8);
    int k = idx >> 4, n4 = (idx & 15) << 2;
    float4 v = *(const float4*)&W[(size_t)(k0 + k) * N + n0 + n4];
    Tile[k][n4 + 0] = v.x; Tile[k][n4 + 1] = v.y;
    Tile[k][n4 + 2] = v.z; Tile[k][n4 + 3] = v.w;
  }
  __syncthreads();
#pragma unroll
  for (int i = 0; i < 4; ++i) {
    int idx = t + (i << 8);
    int n = idx >> 4, k4 = (idx & 15) << 2;
    sx4 h, lo;
#pragma unroll
    for (int j = 0; j < 4; ++j) {
      float v = Tile[k4 + j][n];
      short hh = f2bf(v);
      h[j] = hh;
      lo[j] = f2bf(v - bf2f(hh));
    }
    int kk = k0 + k4, nn = n0 + n;
    size_t dst;
    if constexpr (KT)
      dst = ((size_t)(kk >> 5) * N << 5) + ((size_t)nn << 5) + (kk & 31);
    else
      dst = (size_t)nn * K + kk;
    *(sx4*)&Th[dst] = h;
    *(sx4*)&Tl[dst] = lo;
  }
}

// ---------- wide-N split-bf16 GEMM: C[M,256] = A[M,K] @ B[K,256] + bias ----------
template<int AM, int EP>
__global__ __launch_bounds__(256) void gemm_wide_kernel(
    const void* __restrict__ Av, const short* __restrict__ Alo,
    const short* __restrict__ Bth, const short* __restrict__ Btl,
    const float* __restrict__ bias, float* __restrict__ C,
    short* __restrict__ qout, int M, int K)
{
  __shared__ short Bhs[256][36];
  __shared__ short Bls[256][36];
  const int t = threadIdx.x;
  const int bm = blockIdx.x << 6;
  const int w = t >> 6, l = t & 63, g = l >> 4, c = l & 15;
  const int g8 = g << 3;
  const int arow = bm + (w << 4) + c;
  const int srow = t >> 2;
  const int skc  = (t & 3) << 3;

  sx8 pb0h, pb1h, pb2h, pb3h, pb0l, pb1l, pb2l, pb3l;
  auto LOADB = [&](int k0) {
    const size_t tb = ((size_t)(k0 >> 5) << 13) + ((size_t)t << 3);
    pb0h = *(const sx8*)&Bth[tb];         pb1h = *(const sx8*)&Bth[tb + 2048];
    pb2h = *(const sx8*)&Bth[tb + 4096];  pb3h = *(const sx8*)&Bth[tb + 6144];
    pb0l = *(const sx8*)&Btl[tb];         pb1l = *(const sx8*)&Btl[tb + 2048];
    pb2l = *(const sx8*)&Btl[tb + 4096];  pb3l = *(const sx8*)&Btl[tb + 6144];
  };

  float4 pa0, pa1; sx8 pah, pal;
  auto LOADA = [&](int k0) {
    if constexpr (AM == 2) {
      size_t idx = ((size_t)(arow >> 12) << 20) + ((size_t)(k0 >> 5) << 17)
                 + ((size_t)(arow & 4095) << 5) + g8;
      pah = *(const sx8*)&((const short*)Av)[idx];
      pal = *(const sx8*)&Alo[idx];
    } else {
      const float* ap = (const float*)Av + (size_t)arow * K + k0 + g8;
      pa0 = *(const float4*)ap;
      pa1 = *(const float4*)(ap + 4);
    }
  };

  fx4 acc[16];
#pragma unroll
  for (int j = 0; j < 16; ++j) acc[j] = fx4{0.f, 0.f, 0.f, 0.f};

  LOADB(0); LOADA(0);
  for (int k0 = 0; k0 < K; k0 += 32) {
    *(sx8*)&Bhs[srow][skc]       = pb0h;
    *(sx8*)&Bhs[64 + srow][skc]  = pb1h;
    *(sx8*)&Bhs[128 + srow][skc] = pb2h;
    *(sx8*)&Bhs[192 + srow][skc] = pb3h;
    *(sx8*)&Bls[srow][skc]       = pb0l;
    *(sx8*)&Bls[64 + srow][skc]  = pb1l;
    *(sx8*)&Bls[128 + srow][skc] = pb2l;
    *(sx8*)&Bls[192 + srow][skc] = pb3l;
    sx8 ah, al;
    if constexpr (AM == 2) { ah = pah; al = pal; }
    else {
      ah[0]=f2bf(pa0.x); al[0]=f2bf(pa0.x-bf2f(ah[0]));
      ah[1]=f2bf(pa0.y); al[1]=f2bf(pa0.y-bf2f(ah[1]));
      ah[2]=f2bf(pa0.z); al[2]=f2bf(pa0.z-bf2f(ah[2]));
      ah[3]=f2bf(pa0.w); al[3]=f2bf(pa0.w-bf2f(ah[3]));
      ah[4]=f2bf(pa1.x); al[4]=f2bf(pa1.x-bf2f(ah[4]));
      ah[5]=f2bf(pa1.y); al[5]=f2bf(pa1.y-bf2f(ah[5]));
      ah[6]=f2bf(pa1.z); al[6]=f2bf(pa1.z-bf2f(ah[6]));
      ah[7]=f2bf(pa1.w); al[7]=f2bf(pa1.w-bf2f(ah[7]));
    }
    __syncthreads();
    if (k0 + 32 < K) { LOADB(k0 + 32); LOADA(k0 + 32); }
#pragma unroll
    for (int j = 0; j < 16; ++j) {
      sx8 bh = *(const sx8*)&Bhs[(j << 4) + c][g8];
      sx8 bl = *(const sx8*)&Bls[(j << 4) + c][g8];
      acc[j] = __builtin_amdgcn_mfma_f32_16x16x32_bf16(ah, bh, acc[j], 0, 0, 0);
      acc[j] = __builtin_amdgcn_mfma_f32_16x16x32_bf16(al, bh, acc[j], 0, 0, 0);
      acc[j] = __builtin_amdgcn_mfma_f32_16x16x32_bf16(ah, bl, acc[j], 0, 0, 0);
    }
    __syncthreads();
  }

  const int orow = bm + (w << 4) + (g << 2);
#pragma unroll
  for (int j = 0; j < 16; ++j) {
    const int col = (j << 4) + c;
    const float bb = bias[col];
    if constexpr (EP == 0) {
#pragma unroll
      for (int i = 0; i < 4; ++i)
        C[(size_t)(orow + i) * 256 + col] = acc[j][i] + bb;
    } else {  // EP == 3: q bf16 prescaled head-major
      const int h = col >> 5, d = col & 31;
#pragma unroll
      for (int i = 0; i < 4; ++i) {
        int r = orow + i;
        qout[((size_t)(((r >> 12) << 3) + h) * 4096 + (r & 4095)) * 32 + d]
            = f2bf((acc[j][i] + bb) * QSCALE);
      }
    }
  }
}

// ---------- classic split-bf16 GEMM (f32 A): conv partials + kv ----------
template<bool GATHER, int EPI>
__global__ __launch_bounds__(256) void gemm_split_kernel(
    const float* __restrict__ A, const short* __restrict__ Bth,
    const short* __restrict__ Btl, const float* __restrict__ bias,
    float* __restrict__ C, short* __restrict__ kout, short* __restrict__ vout,
    int M, int N, int K)
{
  __shared__ short Ah[64][40], Al[64][40], Bh[64][40], Bl[64][40];
  const int t = threadIdx.x;
  const int bm = blockIdx.y << 6, bn = blockIdx.x << 6;
  const int ar = t >> 2, ak = (t & 3) << 3;
  const int bc = t >> 2, bk = (t & 3) << 3;

  int sp_base = 0;
  if (GATHER) {
    int gr = bm + ar;
    int b = gr >> 8, mm2 = gr & 255;
    int oh = mm2 >> 4, ow = mm2 & 15;
    sp_base = b * 4096 + oh * 256 + ow * 4;
  }
  const size_t brow = (size_t)(bn + bc) * K;

  const int KS = K / gridDim.z;
  const int kbeg = blockIdx.z * KS, kend = kbeg + KS;

  float4 pa0, pa1; sx8 pbh, pbl;
  auto LOADG = [&](int k0) {
    int k = k0 + ak;
    const float* ap;
    if (GATHER) {
      int pos = k >> 8, ci = k & 255;
      ap = &A[(size_t)(sp_base + ((pos >> 2) << 6) + (pos & 3)) * 256 + ci];
    } else {
      ap = &A[(size_t)(bm + ar) * K + k];
    }
    pa0 = *(const float4*)ap;
    pa1 = *(const float4*)(ap + 4);
    pbh = *(const sx8*)&Bth[brow + k0 + bk];
    pbl = *(const sx8*)&Btl[brow + k0 + bk];
  };

  const int w = t >> 6, l = t & 63, g = l >> 4, c = l & 15;
  const int wr = w >> 1, wc = w & 1;
  const int ra0 = (wr << 5) + c, ra1 = ra0 + 16;
  const int cb0 = (wc << 5) + c, cb1 = cb0 + 16;
  const int g8 = g << 3;

  fx4 acc00 = {0.f,0.f,0.f,0.f}, acc01 = acc00, acc10 = acc00, acc11 = acc00;

  LOADG(kbeg);
  for (int k0 = kbeg; k0 < kend; k0 += 32) {
    sx4 AH0, AL0, AH1, AL1;
    AH0[0]=f2bf(pa0.x); AL0[0]=f2bf(pa0.x-bf2f(AH0[0]));
    AH0[1]=f2bf(pa0.y); AL0[1]=f2bf(pa0.y-bf2f(AH0[1]));
    AH0[2]=f2bf(pa0.z); AL0[2]=f2bf(pa0.z-bf2f(AH0[2]));
    AH0[3]=f2bf(pa0.w); AL0[3]=f2bf(pa0.w-bf2f(AH0[3]));
    AH1[0]=f2bf(pa1.x); AL1[0]=f2bf(pa1.x-bf2f(AH1[0]));
    AH1[1]=f2bf(pa1.y); AL1[1]=f2bf(pa1.y-bf2f(AH1[1]));
    AH1[2]=f2bf(pa1.z); AL1[2]=f2bf(pa1.z-bf2f(AH1[2]));
    AH1[3]=f2bf(pa1.w); AL1[3]=f2bf(pa1.w-bf2f(AH1[3]));
    *(sx4*)&Ah[ar][ak]     = AH0;  *(sx4*)&Ah[ar][ak + 4] = AH1;
    *(sx4*)&Al[ar][ak]     = AL0;  *(sx4*)&Al[ar][ak + 4] = AL1;
    *(sx8*)&Bh[bc][bk] = pbh;      *(sx8*)&Bl[bc][bk] = pbl;
    __syncthreads();
    if (k0 + 32 < kend) LOADG(k0 + 32);

    sx8 a0h = *(const sx8*)&Ah[ra0][g8];
    sx8 a0l = *(const sx8*)&Al[ra0][g8];
    sx8 a1h = *(const sx8*)&Ah[ra1][g8];
    sx8 a1l = *(const sx8*)&Al[ra1][g8];
    sx8 b0h = *(const sx8*)&Bh[cb0][g8];
    sx8 b0l = *(const sx8*)&Bl[cb0][g8];
    sx8 b1h = *(const sx8*)&Bh[cb1][g8];
    sx8 b1l = *(const sx8*)&Bl[cb1][g8];

    acc00 = __builtin_amdgcn_mfma_f32_16x16x32_bf16(a0h, b0h, acc00, 0, 0, 0);
    acc01 = __builtin_amdgcn_mfma_f32_16x16x32_bf16(a0h, b1h, acc01, 0, 0, 0);
    acc10 = __builtin_amdgcn_mfma_f32_16x16x32_bf16(a1h, b0h, acc10, 0, 0, 0);
    acc11 = __builtin_amdgcn_mfma_f32_16x16x32_bf16(a1h, b1h, acc11, 0, 0, 0);
    acc00 = __builtin_amdgcn_mfma_f32_16x16x32_bf16(a0l, b0h, acc00, 0, 0, 0);
    acc01 = __builtin_amdgcn_mfma_f32_16x16x32_bf16(a0l, b1h, acc01, 0, 0, 0);
    acc10 = __builtin_amdgcn_mfma_f32_16x16x32_bf16(a1l, b0h, acc10, 0, 0, 0);
    acc11 = __builtin_amdgcn_mfma_f32_16x16x32_bf16(a1l, b1h, acc11, 0, 0, 0);
    acc00 = __builtin_amdgcn_mfma_f32_16x16x32_bf16(a0h, b0l, acc00, 0, 0, 0);
    acc01 = __builtin_amdgcn_mfma_f32_16x16x32_bf16(a0h, b1l, acc01, 0, 0, 0);
    acc10 = __builtin_amdgcn_mfma_f32_16x16x32_bf16(a1h, b0l, acc10, 0, 0, 0);
    acc11 = __builtin_amdgcn_mfma_f32_16x16x32_bf16(a1h, b1l, acc11, 0, 0, 0);
    __syncthreads();
  }

  const int col0 = bn + (wc << 5);
  const int row0 = bm + (wr << 5) + (g << 2);
  if constexpr (EPI == 1) {
    float* Cz = C + (size_t)blockIdx.z * M * N;
#pragma unroll
    for (int i = 0; i < 4; ++i) {
      Cz[(size_t)(row0 + i) * N + col0 + c]           = acc00[i];
      Cz[(size_t)(row0 + i) * N + col0 + 16 + c]      = acc01[i];
      Cz[(size_t)(row0 + 16 + i) * N + col0 + c]      = acc10[i];
      Cz[(size_t)(row0 + 16 + i) * N + col0 + 16 + c] = acc11[i];
    }
  } else {  // EPI == 2: kv emit -> K/V [b*8+h][m][32] bf16
    const float b0 = bias[col0 + c], b1 = bias[col0 + 16 + c];
    auto emit = [&](int row, int n, float v) {
      int b = row >> 8, m = row & 255;
      short* dst = (n < 256) ? kout : vout;
      int nn = n & 255;
      int h = nn >> 5, d = nn & 31;
      dst[(size_t)(((b << 3) + h) * 256 + m) * 32 + d] = f2bf(v);
    };
#pragma unroll
    for (int i = 0; i < 4; ++i) {
      emit(row0 + i,      col0 + c,      acc00[i] + b0);
      emit(row0 + i,      col0 + 16 + c, acc01[i] + b1);
      emit(row0 + 16 + i, col0 + c,      acc10[i] + b0);
      emit(row0 + 16 + i, col0 + 16 + c, acc11[i] + b1);
    }
  }
}

// -------- fused K-split reduce (8 parts) + bias + LayerNorm: xs row per block --------
__global__ __launch_bounds__(256) void ln_reduce_kernel(
    const float* __restrict__ parts, const float* __restrict__ bias,
    const float* __restrict__ g, const float* __restrict__ bta,
    float* __restrict__ xs)
{
  const int row = blockIdx.x, t = threadIdx.x;
  const size_t MN = (size_t)4096 * 256;
  const size_t off = (size_t)row * CC + t;
  float v = bias[t];
#pragma unroll
  for (int p = 0; p < 8; ++p) v += parts[p * MN + off];
  float s = v, s2 = v * v;
#pragma unroll
  for (int offs = 32; offs; offs >>= 1) {
    s  += __shfl_xor(s,  offs, 64);
    s2 += __shfl_xor(s2, offs, 64);
  }
  __shared__ float red[8];
  const int w = t >> 6, lane = t & 63;
  if (lane == 0) { red[w] = s; red[4 + w] = s2; }
  __syncthreads();
  float ts  = red[0] + red[1] + red[2] + red[3];
  float ts2 = red[4] + red[5] + red[6] + red[7];
  float mu  = ts * (1.0f / 256.0f);
  float var = ts2 * (1.0f / 256.0f) - mu * mu;
  float o = (v - mu) * rsqrtf(var + 1e-6f) * g[t] + bta[t];
  xs[off] = o;
}

// ---------------- MFMA attention v4 + setprio: k-permuted P/V, cvt_pk packed P stores ----------------
__global__ __launch_bounds__(256, 3) void attn_mfma4_kernel(
    short* __restrict__ qob, short* __restrict__ olo,
    const short* __restrict__ kbf, const short* __restrict__ vbf)
{
  __shared__ short Vt[32 * 264];       // V^T [d][m'], stride 264
  __shared__ short Ps[4 * 16 * 264];   // per-wave P [16 rows][m'], stride 264

  const int tid = threadIdx.x;
  const int bid = blockIdx.x;
  const int nt = bid & 63, h = (bid >> 6) & 7, b = bid >> 9;
  const int n0 = nt << 6;
  const int bh = (b << 3) + h;
  const short* kb = kbf + (size_t)bh * 8192;
  const short* vb = vbf + (size_t)bh * 8192;

  // ---- stage V^T with m-permute ----
  {
    const int msrc = ((tid & 15) << 4) | (tid >> 4);
    sx8 v0 = *(const sx8*)&vb[msrc * 32 + 0];
    sx8 v1 = *(const sx8*)&vb[msrc * 32 + 8];
    sx8 v2 = *(const sx8*)&vb[msrc * 32 + 16];
    sx8 v3 = *(const sx8*)&vb[msrc * 32 + 24];
#pragma unroll
    for (int e = 0; e < 8; ++e) {
      Vt[(e)      * 264 + tid] = v0[e];
      Vt[(8 + e)  * 264 + tid] = v1[e];
      Vt[(16 + e) * 264 + tid] = v2[e];
      Vt[(24 + e) * 264 + tid] = v3[e];
    }
  }

  const int w = tid >> 6, l = tid & 63;
  const int g = l >> 4, c = l & 15;

  // ---- Q A-fragment: direct bf16 load ----
  sx8 aq = *(const sx8*)&qob[((size_t)bh * 4096 + n0 + w * 16 + c) * 32 + (g << 3)];

  // ---- S = Q K^T ----
  fx4 acc[16];
  __builtin_amdgcn_s_setprio(1);
#pragma unroll
  for (int j = 0; j < 16; ++j) {
    sx8 bk = *(const sx8*)&kb[(j * 16 + c) * 32 + (g << 3)];
    fx4 z = {0.f, 0.f, 0.f, 0.f};
    acc[j] = __builtin_amdgcn_mfma_f32_16x16x32_bf16(aq, bk, z, 0, 0, 0);
  }
  __builtin_amdgcn_s_setprio(0);

  // ---- in-register softmax ----
  float mx[4], sm[4];
#pragma unroll
  for (int i = 0; i < 4; ++i) {
    float m0 = acc[0][i];
#pragma unroll
    for (int j = 1; j < 16; ++j) m0 = fmaxf(m0, acc[j][i]);
    m0 = fmaxf(m0, __shfl_xor(m0, 1, 64));
    m0 = fmaxf(m0, __shfl_xor(m0, 2, 64));
    m0 = fmaxf(m0, __shfl_xor(m0, 4, 64));
    m0 = fmaxf(m0, __shfl_xor(m0, 8, 64));
    mx[i] = m0;
  }
#pragma unroll
  for (int i = 0; i < 4; ++i) {
    float s0 = 0.f;
#pragma unroll
    for (int j = 0; j < 16; ++j) {
      float p = fexp2(acc[j][i] - mx[i]);
      acc[j][i] = p; s0 += p;
    }
    s0 += __shfl_xor(s0, 1, 64);
    s0 += __shfl_xor(s0, 2, 64);
    s0 += __shfl_xor(s0, 4, 64);
    s0 += __shfl_xor(s0, 8, 64);
    sm[i] = s0;
  }

  // ---- P -> LDS: contiguous per thread; 8 cvt_pk + 2 b128 per row ----
  const int pbase = (w << 4) * 264;
#pragma unroll
  for (int i = 0; i < 4; ++i) {
    unsigned p0 = cvtpk_bf16(acc[0][i],  acc[1][i]);
    unsigned p1 = cvtpk_bf16(acc[2][i],  acc[3][i]);
    unsigned p2 = cvtpk_bf16(acc[4][i],  acc[5][i]);
    unsigned p3 = cvtpk_bf16(acc[6][i],  acc[7][i]);
    unsigned p4 = cvtpk_bf16(acc[8][i],  acc[9][i]);
    unsigned p5 = cvtpk_bf16(acc[10][i], acc[11][i]);
    unsigned p6 = cvtpk_bf16(acc[12][i], acc[13][i]);
    unsigned p7 = cvtpk_bf16(acc[14][i], acc[15][i]);
    unsigned* dst = (unsigned*)&Ps[pbase + ((g << 2) + i) * 264 + (c << 4)];
    uint4 lo4; lo4.x = p0; lo4.y = p1; lo4.z = p2; lo4.w = p3;
    uint4 hi4; hi4.x = p4; hi4.y = p5; hi4.z = p6; hi4.w = p7;
    *(uint4*)dst       = lo4;
    *(uint4*)(dst + 4) = hi4;
  }

  __syncthreads();

  // ---- O = P V over permuted k ----
  fx4 o0 = {0.f,0.f,0.f,0.f}, o1 = {0.f,0.f,0.f,0.f};
  __builtin_amdgcn_s_setprio(1);
#pragma unroll
  for (int s = 0; s < 8; ++s) {
    sx8 ap  = *(const sx8*)&Ps[pbase + c * 264 + (s << 5) + (g << 3)];
    sx8 bv0 = *(const sx8*)&Vt[(c)      * 264 + (s << 5) + (g << 3)];
    sx8 bv1 = *(const sx8*)&Vt[(16 + c) * 264 + (s << 5) + (g << 3)];
    o0 = __builtin_amdgcn_mfma_f32_16x16x32_bf16(ap, bv0, o0, 0, 0, 0);
    o1 = __builtin_amdgcn_mfma_f32_16x16x32_bf16(ap, bv1, o1, 0, 0, 0);
  }
  __builtin_amdgcn_s_setprio(0);

  // ---- normalize, split to bf16 hi/lo, write [b*8+h][n][32] ----
#pragma unroll
  for (int i = 0; i < 4; ++i) {
    float inv = frcp(sm[i]);
    int n = n0 + w * 16 + (g << 2) + i;
    size_t base = ((size_t)bh * 4096 + n) * 32;
    float v0 = o0[i] * inv, v1 = o1[i] * inv;
    short h0 = f2bf(v0), h1 = f2bf(v1);
    qob[base + c]      = h0;  olo[base + c]      = f2bf(v0 - bf2f(h0));
    qob[base + 16 + c] = h1;  olo[base + 16 + c] = f2bf(v1 - bf2f(h1));
  }
}

extern "C" void kernel_launch(void* const* d_in, const int* in_sizes, int n_in,
                              void* d_out, int out_size, void* d_ws, size_t ws_size,
                              hipStream_t stream) {
  const float* x      = (const float*)d_in[0];
  const float* q_w    = (const float*)d_in[1];
  const float* q_b    = (const float*)d_in[2];
  const float* kv_w   = (const float*)d_in[3];
  const float* kv_b   = (const float*)d_in[4];
  const float* sr_w   = (const float*)d_in[5];
  const float* sr_b   = (const float*)d_in[6];
  const float* norm_g = (const float*)d_in[7];
  const float* norm_b = (const float*)d_in[8];
  const float* proj_w = (const float*)d_in[9];
  const float* proj_b = (const float*)d_in[10];
  float* out = (float*)d_out;

  // workspace
  float* xsbuf = (float*)d_ws;                     // 4 MB
  short* qbf   = (short*)(xsbuf + 1048576);        // 32 MB: q bf16, then O-hi
  short* olo   = qbf + 16777216;                   // 32 MB: O-lo
  short* kbf   = olo + 16777216;                   // 4 MB
  short* vbf   = kbf + 2097152;                    // 4 MB
  short* qwt_h  = vbf + 2097152;
  short* qwt_l  = qwt_h + 65536;
  short* kvwt_h = qwt_l + 65536;
  short* kvwt_l = kvwt_h + 131072;
  short* pwt_h  = kvwt_l + 131072;
  short* pwt_l  = pwt_h + 65536;
  short* swt_h  = pwt_l + 65536;
  short* swt_l  = swt_h + 1048576;
  // d_out (64 MB) as early scratch: conv K-split partials (8 x 4 MB = 32 MB)
  float* partf = out;

  dim3 blk(256);

  wsplit_kernel<true><<<dim3(CC/64, CC/64), blk, 0, stream>>>(q_w, qwt_h, qwt_l, CC, CC);
  wsplit_kernel<false><<<dim3(2*CC/64, CC/64), blk, 0, stream>>>(kv_w, kvwt_h, kvwt_l, CC, 2*CC);
  wsplit_kernel<true><<<dim3(CC/64, CC/64), blk, 0, stream>>>(proj_w, pwt_h, pwt_l, CC, CC);
  wsplit_kernel<false><<<dim3(CC/64, 4096/64), blk, 0, stream>>>(sr_w, swt_h, swt_l, 4096, CC);

  // 1) q = x @ q_w + q_b -> bf16 prescaled [b*8+h][n][32]
  gemm_wide_kernel<0,3><<<dim3((B_*NN)/64), blk, 0, stream>>>(
      x, nullptr, qwt_h, qwt_l, q_b, nullptr, qbf, B_*NN, CC);

  // 2) conv (gathered GEMM, K=4096), K-split x8 -> f32 partials in d_out
  gemm_split_kernel<true,1><<<dim3(CC/64, (B_*MM)/64, 8), blk, 0, stream>>>(
      x, swt_h, swt_l, sr_b, partf, nullptr, nullptr, B_*MM, CC, 4096);

  // 3) fused reduce (8 parts) + bias + LayerNorm
  ln_reduce_kernel<<<B_ * MM, blk, 0, stream>>>(partf, sr_b, norm_g, norm_b, xsbuf);

  // 4) kv = xs @ kv_w + kv_b -> bf16 K/V [b*8+h][m][32]
  gemm_split_kernel<false,2><<<dim3((2*CC)/64, (B_*MM)/64, 1), blk, 0, stream>>>(
      xsbuf, kvwt_h, kvwt_l, kv_b, nullptr, kbf, vbf, B_*MM, 2*CC, CC);

  // 5) attention: reads qbf, writes O-hi over qbf + O-lo
  attn_mfma4_kernel<<<B_ * NH * (NN / 64), blk, 0, stream>>>(qbf, olo, kbf, vbf);

  // 6) out = O @ proj_w + proj_b
  gemm_wide_kernel<2,0><<<dim3((B_*NN)/64), blk, 0, stream>>>(
      qbf, olo, pwt_h, pwt_l, proj_b, out, nullptr, B_*NN, CC);
}

// Round 17
// 231.536 us; speedup vs baseline: 1.4820x; 1.0224x over previous
//
#include <hip/hip_runtime.h>
#include <math.h>

#define B_   16
#define CC   256
#define NN   4096   // 64*64
#define MM   256    // 16*16
#define NH   8
#define HD   32
// scale * log2(e): softmax done in base-2
#define QSCALE (0.17677669529663687f * 1.4426950408889634f)

typedef float fx4 __attribute__((ext_vector_type(4)));
typedef short sx4 __attribute__((ext_vector_type(4)));
typedef short sx8 __attribute__((ext_vector_type(8)));

__device__ inline short f2bf(float f) {
  unsigned u = __builtin_bit_cast(unsigned, f);
  u += 0x7FFFu + ((u >> 16) & 1u);   // RNE
  return (short)(u >> 16);
}
__device__ inline float bf2f(short s) {
  unsigned u = ((unsigned)(unsigned short)s) << 16;
  return __builtin_bit_cast(float, u);
}
__device__ inline unsigned cvtpk_bf16(float a, float b) {
  unsigned r;
  asm("v_cvt_pk_bf16_f32 %0, %1, %2" : "=v"(r) : "v"(a), "v"(b));
  return r;
}
__device__ inline float fexp2(float x) {
#if __has_builtin(__builtin_amdgcn_exp2f)
  return __builtin_amdgcn_exp2f(x);
#else
  return exp2f(x);
#endif
}
__device__ inline float frcp(float x) {
#if __has_builtin(__builtin_amdgcn_rcpf)
  return __builtin_amdgcn_rcpf(x);
#else
  return 1.0f / x;
#endif
}

// ---------- weight transpose + bf16 split ----------
// KT=false: W[K][N] f32 -> Th/Tl[N][K] bf16 (row-major-T).
// KT=true:  W[K][N] f32 -> Th/Tl[K/32][N][32] bf16 (k-tile-major, coalesced loads).
template<bool KT>
__global__ __launch_bounds__(256) void wsplit_kernel(
    const float* __restrict__ W, short* __restrict__ Th, short* __restrict__ Tl,
    int K, int N)
{
  __shared__ float Tile[64][65];
  const int t = threadIdx.x;
  const int k0 = blockIdx.y << 6, n0 = blockIdx.x << 6;
#pragma unroll
  for (int i = 0; i < 4; ++i) {
    int idx = t + (i << 8);
    int k = idx >> 4, n4 = (idx & 15) << 2;
    float4 v = *(const float4*)&W[(size_t)(k0 + k) * N + n0 + n4];
    Tile[k][n4 + 0] = v.x; Tile[k][n4 + 1] = v.y;
    Tile[k][n4 + 2] = v.z; Tile[k][n4 + 3] = v.w;
  }
  __syncthreads();
#pragma unroll
  for (int i = 0; i < 4; ++i) {
    int idx = t + (i << 8);
    int n = idx >> 4, k4 = (idx & 15) << 2;
    sx4 h, lo;
#pragma unroll
    for (int j = 0; j < 4; ++j) {
      float v = Tile[k4 + j][n];
      short hh = f2bf(v);
      h[j] = hh;
      lo[j] = f2bf(v - bf2f(hh));
    }
    int kk = k0 + k4, nn = n0 + n;
    size_t dst;
    if constexpr (KT)
      dst = ((size_t)(kk >> 5) * N << 5) + ((size_t)nn << 5) + (kk & 31);
    else
      dst = (size_t)nn * K + kk;
    *(sx4*)&Th[dst] = h;
    *(sx4*)&Tl[dst] = lo;
  }
}

// ---------- wide-N split-bf16 GEMM: C[M,256] = A[M,K] @ B[K,256] + bias ----------
template<int AM, int EP>
__global__ __launch_bounds__(256) void gemm_wide_kernel(
    const void* __restrict__ Av, const short* __restrict__ Alo,
    const short* __restrict__ Bth, const short* __restrict__ Btl,
    const float* __restrict__ bias, float* __restrict__ C,
    short* __restrict__ qout, int M, int K)
{
  __shared__ short Bhs[256][36];
  __shared__ short Bls[256][36];
  const int t = threadIdx.x;
  const int bm = blockIdx.x << 6;
  const int w = t >> 6, l = t & 63, g = l >> 4, c = l & 15;
  const int g8 = g << 3;
  const int arow = bm + (w << 4) + c;
  const int srow = t >> 2;
  const int skc  = (t & 3) << 3;

  sx8 pb0h, pb1h, pb2h, pb3h, pb0l, pb1l, pb2l, pb3l;
  auto LOADB = [&](int k0) {
    const size_t tb = ((size_t)(k0 >> 5) << 13) + ((size_t)t << 3);
    pb0h = *(const sx8*)&Bth[tb];         pb1h = *(const sx8*)&Bth[tb + 2048];
    pb2h = *(const sx8*)&Bth[tb + 4096];  pb3h = *(const sx8*)&Bth[tb + 6144];
    pb0l = *(const sx8*)&Btl[tb];         pb1l = *(const sx8*)&Btl[tb + 2048];
    pb2l = *(const sx8*)&Btl[tb + 4096];  pb3l = *(const sx8*)&Btl[tb + 6144];
  };

  float4 pa0, pa1; sx8 pah, pal;
  auto LOADA = [&](int k0) {
    if constexpr (AM == 2) {
      size_t idx = ((size_t)(arow >> 12) << 20) + ((size_t)(k0 >> 5) << 17)
                 + ((size_t)(arow & 4095) << 5) + g8;
      pah = *(const sx8*)&((const short*)Av)[idx];
      pal = *(const sx8*)&Alo[idx];
    } else {
      const float* ap = (const float*)Av + (size_t)arow * K + k0 + g8;
      pa0 = *(const float4*)ap;
      pa1 = *(const float4*)(ap + 4);
    }
  };

  fx4 acc[16];
#pragma unroll
  for (int j = 0; j < 16; ++j) acc[j] = fx4{0.f, 0.f, 0.f, 0.f};

  LOADB(0); LOADA(0);
  for (int k0 = 0; k0 < K; k0 += 32) {
    *(sx8*)&Bhs[srow][skc]       = pb0h;
    *(sx8*)&Bhs[64 + srow][skc]  = pb1h;
    *(sx8*)&Bhs[128 + srow][skc] = pb2h;
    *(sx8*)&Bhs[192 + srow][skc] = pb3h;
    *(sx8*)&Bls[srow][skc]       = pb0l;
    *(sx8*)&Bls[64 + srow][skc]  = pb1l;
    *(sx8*)&Bls[128 + srow][skc] = pb2l;
    *(sx8*)&Bls[192 + srow][skc] = pb3l;
    sx8 ah, al;
    if constexpr (AM == 2) { ah = pah; al = pal; }
    else {
      ah[0]=f2bf(pa0.x); al[0]=f2bf(pa0.x-bf2f(ah[0]));
      ah[1]=f2bf(pa0.y); al[1]=f2bf(pa0.y-bf2f(ah[1]));
      ah[2]=f2bf(pa0.z); al[2]=f2bf(pa0.z-bf2f(ah[2]));
      ah[3]=f2bf(pa0.w); al[3]=f2bf(pa0.w-bf2f(ah[3]));
      ah[4]=f2bf(pa1.x); al[4]=f2bf(pa1.x-bf2f(ah[4]));
      ah[5]=f2bf(pa1.y); al[5]=f2bf(pa1.y-bf2f(ah[5]));
      ah[6]=f2bf(pa1.z); al[6]=f2bf(pa1.z-bf2f(ah[6]));
      ah[7]=f2bf(pa1.w); al[7]=f2bf(pa1.w-bf2f(ah[7]));
    }
    __syncthreads();
    if (k0 + 32 < K) { LOADB(k0 + 32); LOADA(k0 + 32); }
#pragma unroll
    for (int j = 0; j < 16; ++j) {
      sx8 bh = *(const sx8*)&Bhs[(j << 4) + c][g8];
      sx8 bl = *(const sx8*)&Bls[(j << 4) + c][g8];
      acc[j] = __builtin_amdgcn_mfma_f32_16x16x32_bf16(ah, bh, acc[j], 0, 0, 0);
      acc[j] = __builtin_amdgcn_mfma_f32_16x16x32_bf16(al, bh, acc[j], 0, 0, 0);
      acc[j] = __builtin_amdgcn_mfma_f32_16x16x32_bf16(ah, bl, acc[j], 0, 0, 0);
    }
    __syncthreads();
  }

  const int orow = bm + (w << 4) + (g << 2);
#pragma unroll
  for (int j = 0; j < 16; ++j) {
    const int col = (j << 4) + c;
    const float bb = bias[col];
    if constexpr (EP == 0) {
#pragma unroll
      for (int i = 0; i < 4; ++i)
        C[(size_t)(orow + i) * 256 + col] = acc[j][i] + bb;
    } else {  // EP == 3: q bf16 prescaled head-major
      const int h = col >> 5, d = col & 31;
#pragma unroll
      for (int i = 0; i < 4; ++i) {
        int r = orow + i;
        qout[((size_t)(((r >> 12) << 3) + h) * 4096 + (r & 4095)) * 32 + d]
            = f2bf((acc[j][i] + bb) * QSCALE);
      }
    }
  }
}

// ---------- classic split-bf16 GEMM (f32 A): conv partials + kv ----------
template<bool GATHER, int EPI>
__global__ __launch_bounds__(256) void gemm_split_kernel(
    const float* __restrict__ A, const short* __restrict__ Bth,
    const short* __restrict__ Btl, const float* __restrict__ bias,
    float* __restrict__ C, short* __restrict__ kout, short* __restrict__ vout,
    int M, int N, int K)
{
  __shared__ short Ah[64][40], Al[64][40], Bh[64][40], Bl[64][40];
  const int t = threadIdx.x;
  const int bm = blockIdx.y << 6, bn = blockIdx.x << 6;
  const int ar = t >> 2, ak = (t & 3) << 3;
  const int bc = t >> 2, bk = (t & 3) << 3;

  int sp_base = 0;
  if (GATHER) {
    int gr = bm + ar;
    int b = gr >> 8, mm2 = gr & 255;
    int oh = mm2 >> 4, ow = mm2 & 15;
    sp_base = b * 4096 + oh * 256 + ow * 4;
  }
  const size_t brow = (size_t)(bn + bc) * K;

  const int KS = K / gridDim.z;
  const int kbeg = blockIdx.z * KS, kend = kbeg + KS;

  float4 pa0, pa1; sx8 pbh, pbl;
  auto LOADG = [&](int k0) {
    int k = k0 + ak;
    const float* ap;
    if (GATHER) {
      int pos = k >> 8, ci = k & 255;
      ap = &A[(size_t)(sp_base + ((pos >> 2) << 6) + (pos & 3)) * 256 + ci];
    } else {
      ap = &A[(size_t)(bm + ar) * K + k];
    }
    pa0 = *(const float4*)ap;
    pa1 = *(const float4*)(ap + 4);
    pbh = *(const sx8*)&Bth[brow + k0 + bk];
    pbl = *(const sx8*)&Btl[brow + k0 + bk];
  };

  const int w = t >> 6, l = t & 63, g = l >> 4, c = l & 15;
  const int wr = w >> 1, wc = w & 1;
  const int ra0 = (wr << 5) + c, ra1 = ra0 + 16;
  const int cb0 = (wc << 5) + c, cb1 = cb0 + 16;
  const int g8 = g << 3;

  fx4 acc00 = {0.f,0.f,0.f,0.f}, acc01 = acc00, acc10 = acc00, acc11 = acc00;

  LOADG(kbeg);
  for (int k0 = kbeg; k0 < kend; k0 += 32) {
    sx4 AH0, AL0, AH1, AL1;
    AH0[0]=f2bf(pa0.x); AL0[0]=f2bf(pa0.x-bf2f(AH0[0]));
    AH0[1]=f2bf(pa0.y); AL0[1]=f2bf(pa0.y-bf2f(AH0[1]));
    AH0[2]=f2bf(pa0.z); AL0[2]=f2bf(pa0.z-bf2f(AH0[2]));
    AH0[3]=f2bf(pa0.w); AL0[3]=f2bf(pa0.w-bf2f(AH0[3]));
    AH1[0]=f2bf(pa1.x); AL1[0]=f2bf(pa1.x-bf2f(AH1[0]));
    AH1[1]=f2bf(pa1.y); AL1[1]=f2bf(pa1.y-bf2f(AH1[1]));
    AH1[2]=f2bf(pa1.z); AL1[2]=f2bf(pa1.z-bf2f(AH1[2]));
    AH1[3]=f2bf(pa1.w); AL1[3]=f2bf(pa1.w-bf2f(AH1[3]));
    *(sx4*)&Ah[ar][ak]     = AH0;  *(sx4*)&Ah[ar][ak + 4] = AH1;
    *(sx4*)&Al[ar][ak]     = AL0;  *(sx4*)&Al[ar][ak + 4] = AL1;
    *(sx8*)&Bh[bc][bk] = pbh;      *(sx8*)&Bl[bc][bk] = pbl;
    __syncthreads();
    if (k0 + 32 < kend) LOADG(k0 + 32);

    sx8 a0h = *(const sx8*)&Ah[ra0][g8];
    sx8 a0l = *(const sx8*)&Al[ra0][g8];
    sx8 a1h = *(const sx8*)&Ah[ra1][g8];
    sx8 a1l = *(const sx8*)&Al[ra1][g8];
    sx8 b0h = *(const sx8*)&Bh[cb0][g8];
    sx8 b0l = *(const sx8*)&Bl[cb0][g8];
    sx8 b1h = *(const sx8*)&Bh[cb1][g8];
    sx8 b1l = *(const sx8*)&Bl[cb1][g8];

    acc00 = __builtin_amdgcn_mfma_f32_16x16x32_bf16(a0h, b0h, acc00, 0, 0, 0);
    acc01 = __builtin_amdgcn_mfma_f32_16x16x32_bf16(a0h, b1h, acc01, 0, 0, 0);
    acc10 = __builtin_amdgcn_mfma_f32_16x16x32_bf16(a1h, b0h, acc10, 0, 0, 0);
    acc11 = __builtin_amdgcn_mfma_f32_16x16x32_bf16(a1h, b1h, acc11, 0, 0, 0);
    acc00 = __builtin_amdgcn_mfma_f32_16x16x32_bf16(a0l, b0h, acc00, 0, 0, 0);
    acc01 = __builtin_amdgcn_mfma_f32_16x16x32_bf16(a0l, b1h, acc01, 0, 0, 0);
    acc10 = __builtin_amdgcn_mfma_f32_16x16x32_bf16(a1l, b0h, acc10, 0, 0, 0);
    acc11 = __builtin_amdgcn_mfma_f32_16x16x32_bf16(a1l, b1h, acc11, 0, 0, 0);
    acc00 = __builtin_amdgcn_mfma_f32_16x16x32_bf16(a0h, b0l, acc00, 0, 0, 0);
    acc01 = __builtin_amdgcn_mfma_f32_16x16x32_bf16(a0h, b1l, acc01, 0, 0, 0);
    acc10 = __builtin_amdgcn_mfma_f32_16x16x32_bf16(a1h, b0l, acc10, 0, 0, 0);
    acc11 = __builtin_amdgcn_mfma_f32_16x16x32_bf16(a1h, b1l, acc11, 0, 0, 0);
    __syncthreads();
  }

  const int col0 = bn + (wc << 5);
  const int row0 = bm + (wr << 5) + (g << 2);
  if constexpr (EPI == 1) {
    float* Cz = C + (size_t)blockIdx.z * M * N;
#pragma unroll
    for (int i = 0; i < 4; ++i) {
      Cz[(size_t)(row0 + i) * N + col0 + c]           = acc00[i];
      Cz[(size_t)(row0 + i) * N + col0 + 16 + c]      = acc01[i];
      Cz[(size_t)(row0 + 16 + i) * N + col0 + c]      = acc10[i];
      Cz[(size_t)(row0 + 16 + i) * N + col0 + 16 + c] = acc11[i];
    }
  } else {  // EPI == 2: kv emit -> K/V [b*8+h][m][32] bf16
    const float b0 = bias[col0 + c], b1 = bias[col0 + 16 + c];
    auto emit = [&](int row, int n, float v) {
      int b = row >> 8, m = row & 255;
      short* dst = (n < 256) ? kout : vout;
      int nn = n & 255;
      int h = nn >> 5, d = nn & 31;
      dst[(size_t)(((b << 3) + h) * 256 + m) * 32 + d] = f2bf(v);
    };
#pragma unroll
    for (int i = 0; i < 4; ++i) {
      emit(row0 + i,      col0 + c,      acc00[i] + b0);
      emit(row0 + i,      col0 + 16 + c, acc01[i] + b1);
      emit(row0 + 16 + i, col0 + c,      acc10[i] + b0);
      emit(row0 + 16 + i, col0 + 16 + c, acc11[i] + b1);
    }
  }
}

// -------- fused K-split reduce (8 parts) + bias + LayerNorm: xs row per block --------
__global__ __launch_bounds__(256) void ln_reduce_kernel(
    const float* __restrict__ parts, const float* __restrict__ bias,
    const float* __restrict__ g, const float* __restrict__ bta,
    float* __restrict__ xs)
{
  const int row = blockIdx.x, t = threadIdx.x;
  const size_t MN = (size_t)4096 * 256;
  const size_t off = (size_t)row * CC + t;
  float v = bias[t];
#pragma unroll
  for (int p = 0; p < 8; ++p) v += parts[p * MN + off];
  float s = v, s2 = v * v;
#pragma unroll
  for (int offs = 32; offs; offs >>= 1) {
    s  += __shfl_xor(s,  offs, 64);
    s2 += __shfl_xor(s2, offs, 64);
  }
  __shared__ float red[8];
  const int w = t >> 6, lane = t & 63;
  if (lane == 0) { red[w] = s; red[4 + w] = s2; }
  __syncthreads();
  float ts  = red[0] + red[1] + red[2] + red[3];
  float ts2 = red[4] + red[5] + red[6] + red[7];
  float mu  = ts * (1.0f / 256.0f);
  float var = ts2 * (1.0f / 256.0f) - mu * mu;
  float o = (v - mu) * rsqrtf(var + 1e-6f) * g[t] + bta[t];
  xs[off] = o;
}

// ---------------- MFMA attention v4: k-permuted P/V, cvt_pk packed P stores ----------------
__global__ __launch_bounds__(256, 3) void attn_mfma4_kernel(
    short* __restrict__ qob, short* __restrict__ olo,
    const short* __restrict__ kbf, const short* __restrict__ vbf)
{
  __shared__ short Vt[32 * 264];       // V^T [d][m'], stride 264
  __shared__ short Ps[4 * 16 * 264];   // per-wave P [16 rows][m'], stride 264

  const int tid = threadIdx.x;
  const int bid = blockIdx.x;
  const int nt = bid & 63, h = (bid >> 6) & 7, b = bid >> 9;
  const int n0 = nt << 6;
  const int bh = (b << 3) + h;
  const short* kb = kbf + (size_t)bh * 8192;
  const short* vb = vbf + (size_t)bh * 8192;

  // ---- stage V^T with m-permute ----
  {
    const int msrc = ((tid & 15) << 4) | (tid >> 4);
    sx8 v0 = *(const sx8*)&vb[msrc * 32 + 0];
    sx8 v1 = *(const sx8*)&vb[msrc * 32 + 8];
    sx8 v2 = *(const sx8*)&vb[msrc * 32 + 16];
    sx8 v3 = *(const sx8*)&vb[msrc * 32 + 24];
#pragma unroll
    for (int e = 0; e < 8; ++e) {
      Vt[(e)      * 264 + tid] = v0[e];
      Vt[(8 + e)  * 264 + tid] = v1[e];
      Vt[(16 + e) * 264 + tid] = v2[e];
      Vt[(24 + e) * 264 + tid] = v3[e];
    }
  }

  const int w = tid >> 6, l = tid & 63;
  const int g = l >> 4, c = l & 15;

  // ---- Q A-fragment: direct bf16 load ----
  sx8 aq = *(const sx8*)&qob[((size_t)bh * 4096 + n0 + w * 16 + c) * 32 + (g << 3)];

  // ---- S = Q K^T ----
  fx4 acc[16];
#pragma unroll
  for (int j = 0; j < 16; ++j) {
    sx8 bk = *(const sx8*)&kb[(j * 16 + c) * 32 + (g << 3)];
    fx4 z = {0.f, 0.f, 0.f, 0.f};
    acc[j] = __builtin_amdgcn_mfma_f32_16x16x32_bf16(aq, bk, z, 0, 0, 0);
  }

  // ---- in-register softmax ----
  float mx[4], sm[4];
#pragma unroll
  for (int i = 0; i < 4; ++i) {
    float m0 = acc[0][i];
#pragma unroll
    for (int j = 1; j < 16; ++j) m0 = fmaxf(m0, acc[j][i]);
    m0 = fmaxf(m0, __shfl_xor(m0, 1, 64));
    m0 = fmaxf(m0, __shfl_xor(m0, 2, 64));
    m0 = fmaxf(m0, __shfl_xor(m0, 4, 64));
    m0 = fmaxf(m0, __shfl_xor(m0, 8, 64));
    mx[i] = m0;
  }
#pragma unroll
  for (int i = 0; i < 4; ++i) {
    float s0 = 0.f;
#pragma unroll
    for (int j = 0; j < 16; ++j) {
      float p = fexp2(acc[j][i] - mx[i]);
      acc[j][i] = p; s0 += p;
    }
    s0 += __shfl_xor(s0, 1, 64);
    s0 += __shfl_xor(s0, 2, 64);
    s0 += __shfl_xor(s0, 4, 64);
    s0 += __shfl_xor(s0, 8, 64);
    sm[i] = s0;
  }

  // ---- P -> LDS: contiguous per thread; 8 cvt_pk + 2 b128 per row ----
  const int pbase = (w << 4) * 264;
#pragma unroll
  for (int i = 0; i < 4; ++i) {
    unsigned p0 = cvtpk_bf16(acc[0][i],  acc[1][i]);
    unsigned p1 = cvtpk_bf16(acc[2][i],  acc[3][i]);
    unsigned p2 = cvtpk_bf16(acc[4][i],  acc[5][i]);
    unsigned p3 = cvtpk_bf16(acc[6][i],  acc[7][i]);
    unsigned p4 = cvtpk_bf16(acc[8][i],  acc[9][i]);
    unsigned p5 = cvtpk_bf16(acc[10][i], acc[11][i]);
    unsigned p6 = cvtpk_bf16(acc[12][i], acc[13][i]);
    unsigned p7 = cvtpk_bf16(acc[14][i], acc[15][i]);
    unsigned* dst = (unsigned*)&Ps[pbase + ((g << 2) + i) * 264 + (c << 4)];
    uint4 lo4; lo4.x = p0; lo4.y = p1; lo4.z = p2; lo4.w = p3;
    uint4 hi4; hi4.x = p4; hi4.y = p5; hi4.z = p6; hi4.w = p7;
    *(uint4*)dst       = lo4;
    *(uint4*)(dst + 4) = hi4;
  }

  __syncthreads();

  // ---- O = P V over permuted k ----
  fx4 o0 = {0.f,0.f,0.f,0.f}, o1 = {0.f,0.f,0.f,0.f};
#pragma unroll
  for (int s = 0; s < 8; ++s) {
    sx8 ap  = *(const sx8*)&Ps[pbase + c * 264 + (s << 5) + (g << 3)];
    sx8 bv0 = *(const sx8*)&Vt[(c)      * 264 + (s << 5) + (g << 3)];
    sx8 bv1 = *(const sx8*)&Vt[(16 + c) * 264 + (s << 5) + (g << 3)];
    o0 = __builtin_amdgcn_mfma_f32_16x16x32_bf16(ap, bv0, o0, 0, 0, 0);
    o1 = __builtin_amdgcn_mfma_f32_16x16x32_bf16(ap, bv1, o1, 0, 0, 0);
  }

  // ---- normalize, split to bf16 hi/lo, write [b*8+h][n][32] ----
#pragma unroll
  for (int i = 0; i < 4; ++i) {
    float inv = frcp(sm[i]);
    int n = n0 + w * 16 + (g << 2) + i;
    size_t base = ((size_t)bh * 4096 + n) * 32;
    float v0 = o0[i] * inv, v1 = o1[i] * inv;
    short h0 = f2bf(v0), h1 = f2bf(v1);
    qob[base + c]      = h0;  olo[base + c]      = f2bf(v0 - bf2f(h0));
    qob[base + 16 + c] = h1;  olo[base + 16 + c] = f2bf(v1 - bf2f(h1));
  }
}

extern "C" void kernel_launch(void* const* d_in, const int* in_sizes, int n_in,
                              void* d_out, int out_size, void* d_ws, size_t ws_size,
                              hipStream_t stream) {
  const float* x      = (const float*)d_in[0];
  const float* q_w    = (const float*)d_in[1];
  const float* q_b    = (const float*)d_in[2];
  const float* kv_w   = (const float*)d_in[3];
  const float* kv_b   = (const float*)d_in[4];
  const float* sr_w   = (const float*)d_in[5];
  const float* sr_b   = (const float*)d_in[6];
  const float* norm_g = (const float*)d_in[7];
  const float* norm_b = (const float*)d_in[8];
  const float* proj_w = (const float*)d_in[9];
  const float* proj_b = (const float*)d_in[10];
  float* out = (float*)d_out;

  // workspace
  float* xsbuf = (float*)d_ws;                     // 4 MB
  short* qbf   = (short*)(xsbuf + 1048576);        // 32 MB: q bf16, then O-hi
  short* olo   = qbf + 16777216;                   // 32 MB: O-lo
  short* kbf   = olo + 16777216;                   // 4 MB
  short* vbf   = kbf + 2097152;                    // 4 MB
  short* qwt_h  = vbf + 2097152;
  short* qwt_l  = qwt_h + 65536;
  short* kvwt_h = qwt_l + 65536;
  short* kvwt_l = kvwt_h + 131072;
  short* pwt_h  = kvwt_l + 131072;
  short* pwt_l  = pwt_h + 65536;
  short* swt_h  = pwt_l + 65536;
  short* swt_l  = swt_h + 1048576;
  // d_out (64 MB) as early scratch: conv K-split partials (8 x 4 MB = 32 MB)
  float* partf = out;

  dim3 blk(256);

  wsplit_kernel<true><<<dim3(CC/64, CC/64), blk, 0, stream>>>(q_w, qwt_h, qwt_l, CC, CC);
  wsplit_kernel<false><<<dim3(2*CC/64, CC/64), blk, 0, stream>>>(kv_w, kvwt_h, kvwt_l, CC, 2*CC);
  wsplit_kernel<true><<<dim3(CC/64, CC/64), blk, 0, stream>>>(proj_w, pwt_h, pwt_l, CC, CC);
  wsplit_kernel<false><<<dim3(CC/64, 4096/64), blk, 0, stream>>>(sr_w, swt_h, swt_l, 4096, CC);

  // 1) q = x @ q_w + q_b -> bf16 prescaled [b*8+h][n][32]
  gemm_wide_kernel<0,3><<<dim3((B_*NN)/64), blk, 0, stream>>>(
      x, nullptr, qwt_h, qwt_l, q_b, nullptr, qbf, B_*NN, CC);

  // 2) conv (gathered GEMM, K=4096), K-split x8 -> f32 partials in d_out
  gemm_split_kernel<true,1><<<dim3(CC/64, (B_*MM)/64, 8), blk, 0, stream>>>(
      x, swt_h, swt_l, sr_b, partf, nullptr, nullptr, B_*MM, CC, 4096);

  // 3) fused reduce (8 parts) + bias + LayerNorm
  ln_reduce_kernel<<<B_ * MM, blk, 0, stream>>>(partf, sr_b, norm_g, norm_b, xsbuf);

  // 4) kv = xs @ kv_w + kv_b -> bf16 K/V [b*8+h][m][32]
  gemm_split_kernel<false,2><<<dim3((2*CC)/64, (B_*MM)/64, 1), blk, 0, stream>>>(
      xsbuf, kvwt_h, kvwt_l, kv_b, nullptr, kbf, vbf, B_*MM, 2*CC, CC);

  // 5) attention: reads qbf, writes O-hi over qbf + O-lo
  attn_mfma4_kernel<<<B_ * NH * (NN / 64), blk, 0, stream>>>(qbf, olo, kbf, vbf);

  // 6) out = O @ proj_w + proj_b
  gemm_wide_kernel<2,0><<<dim3((B_*NN)/64), blk, 0, stream>>>(
      qbf, olo, pwt_h, pwt_l, proj_b, out, nullptr, B_*NN, CC);
}

// Round 18
// 216.621 us; speedup vs baseline: 1.5840x; 1.0689x over previous
//
#include <hip/hip_runtime.h>
#include <math.h>

#define B_   16
#define CC   256
#define NN   4096   // 64*64
#define MM   256    // 16*16
#define NH   8
#define HD   32
// scale * log2(e): softmax done in base-2
#define QSCALE (0.17677669529663687f * 1.4426950408889634f)

typedef float fx4 __attribute__((ext_vector_type(4)));
typedef short sx4 __attribute__((ext_vector_type(4)));
typedef short sx8 __attribute__((ext_vector_type(8)));

__device__ inline short f2bf(float f) {
  unsigned u = __builtin_bit_cast(unsigned, f);
  u += 0x7FFFu + ((u >> 16) & 1u);   // RNE
  return (short)(u >> 16);
}
__device__ inline float bf2f(short s) {
  unsigned u = ((unsigned)(unsigned short)s) << 16;
  return __builtin_bit_cast(float, u);
}
__device__ inline unsigned cvtpk_bf16(float a, float b) {
  unsigned r;
  asm("v_cvt_pk_bf16_f32 %0, %1, %2" : "=v"(r) : "v"(a), "v"(b));
  return r;
}
__device__ inline float fexp2(float x) {
#if __has_builtin(__builtin_amdgcn_exp2f)
  return __builtin_amdgcn_exp2f(x);
#else
  return exp2f(x);
#endif
}
__device__ inline float frcp(float x) {
#if __has_builtin(__builtin_amdgcn_rcpf)
  return __builtin_amdgcn_rcpf(x);
#else
  return 1.0f / x;
#endif
}

// ---------- weight transpose + bf16 split ----------
// KT=false: W[K][N] f32 -> Th/Tl[N][K] bf16 (row-major-T).
// KT=true:  W[K][N] f32 -> Th/Tl[K/32][N][32] bf16 (k-tile-major, coalesced loads).
template<bool KT>
__global__ __launch_bounds__(256) void wsplit_kernel(
    const float* __restrict__ W, short* __restrict__ Th, short* __restrict__ Tl,
    int K, int N)
{
  __shared__ float Tile[64][65];
  const int t = threadIdx.x;
  const int k0 = blockIdx.y << 6, n0 = blockIdx.x << 6;
#pragma unroll
  for (int i = 0; i < 4; ++i) {
    int idx = t + (i << 8);
    int k = idx >> 4, n4 = (idx & 15) << 2;
    float4 v = *(const float4*)&W[(size_t)(k0 + k) * N + n0 + n4];
    Tile[k][n4 + 0] = v.x; Tile[k][n4 + 1] = v.y;
    Tile[k][n4 + 2] = v.z; Tile[k][n4 + 3] = v.w;
  }
  __syncthreads();
#pragma unroll
  for (int i = 0; i < 4; ++i) {
    int idx = t + (i << 8);
    int n = idx >> 4, k4 = (idx & 15) << 2;
    sx4 h, lo;
#pragma unroll
    for (int j = 0; j < 4; ++j) {
      float v = Tile[k4 + j][n];
      short hh = f2bf(v);
      h[j] = hh;
      lo[j] = f2bf(v - bf2f(hh));
    }
    int kk = k0 + k4, nn = n0 + n;
    size_t dst;
    if constexpr (KT)
      dst = ((size_t)(kk >> 5) * N << 5) + ((size_t)nn << 5) + (kk & 31);
    else
      dst = (size_t)nn * K + kk;
    *(sx4*)&Th[dst] = h;
    *(sx4*)&Tl[dst] = lo;
  }
}

// ---------- wide-N split-bf16 GEMM: C[M,256] = A[M,K] @ B[K,256] + bias ----------
template<int AM, int EP>
__global__ __launch_bounds__(256) void gemm_wide_kernel(
    const void* __restrict__ Av, const short* __restrict__ Alo,
    const short* __restrict__ Bth, const short* __restrict__ Btl,
    const float* __restrict__ bias, float* __restrict__ C,
    short* __restrict__ qout, int M, int K)
{
  __shared__ short Bhs[256][36];
  __shared__ short Bls[256][36];
  const int t = threadIdx.x;
  const int bm = blockIdx.x << 6;
  const int w = t >> 6, l = t & 63, g = l >> 4, c = l & 15;
  const int g8 = g << 3;
  const int arow = bm + (w << 4) + c;
  const int srow = t >> 2;
  const int skc  = (t & 3) << 3;

  sx8 pb0h, pb1h, pb2h, pb3h, pb0l, pb1l, pb2l, pb3l;
  auto LOADB = [&](int k0) {
    const size_t tb = ((size_t)(k0 >> 5) << 13) + ((size_t)t << 3);
    pb0h = *(const sx8*)&Bth[tb];         pb1h = *(const sx8*)&Bth[tb + 2048];
    pb2h = *(const sx8*)&Bth[tb + 4096];  pb3h = *(const sx8*)&Bth[tb + 6144];
    pb0l = *(const sx8*)&Btl[tb];         pb1l = *(const sx8*)&Btl[tb + 2048];
    pb2l = *(const sx8*)&Btl[tb + 4096];  pb3l = *(const sx8*)&Btl[tb + 6144];
  };

  float4 pa0, pa1; sx8 pah, pal;
  auto LOADA = [&](int k0) {
    if constexpr (AM == 2) {
      size_t idx = ((size_t)(arow >> 12) << 20) + ((size_t)(k0 >> 5) << 17)
                 + ((size_t)(arow & 4095) << 5) + g8;
      pah = *(const sx8*)&((const short*)Av)[idx];
      pal = *(const sx8*)&Alo[idx];
    } else {
      const float* ap = (const float*)Av + (size_t)arow * K + k0 + g8;
      pa0 = *(const float4*)ap;
      pa1 = *(const float4*)(ap + 4);
    }
  };

  fx4 acc[16];
#pragma unroll
  for (int j = 0; j < 16; ++j) acc[j] = fx4{0.f, 0.f, 0.f, 0.f};

  LOADB(0); LOADA(0);
  for (int k0 = 0; k0 < K; k0 += 32) {
    *(sx8*)&Bhs[srow][skc]       = pb0h;
    *(sx8*)&Bhs[64 + srow][skc]  = pb1h;
    *(sx8*)&Bhs[128 + srow][skc] = pb2h;
    *(sx8*)&Bhs[192 + srow][skc] = pb3h;
    *(sx8*)&Bls[srow][skc]       = pb0l;
    *(sx8*)&Bls[64 + srow][skc]  = pb1l;
    *(sx8*)&Bls[128 + srow][skc] = pb2l;
    *(sx8*)&Bls[192 + srow][skc] = pb3l;
    sx8 ah, al;
    if constexpr (AM == 2) { ah = pah; al = pal; }
    else {
      ah[0]=f2bf(pa0.x); al[0]=f2bf(pa0.x-bf2f(ah[0]));
      ah[1]=f2bf(pa0.y); al[1]=f2bf(pa0.y-bf2f(ah[1]));
      ah[2]=f2bf(pa0.z); al[2]=f2bf(pa0.z-bf2f(ah[2]));
      ah[3]=f2bf(pa0.w); al[3]=f2bf(pa0.w-bf2f(ah[3]));
      ah[4]=f2bf(pa1.x); al[4]=f2bf(pa1.x-bf2f(ah[4]));
      ah[5]=f2bf(pa1.y); al[5]=f2bf(pa1.y-bf2f(ah[5]));
      ah[6]=f2bf(pa1.z); al[6]=f2bf(pa1.z-bf2f(ah[6]));
      ah[7]=f2bf(pa1.w); al[7]=f2bf(pa1.w-bf2f(ah[7]));
    }
    __syncthreads();
    if (k0 + 32 < K) { LOADB(k0 + 32); LOADA(k0 + 32); }
#pragma unroll
    for (int j = 0; j < 16; ++j) {
      sx8 bh = *(const sx8*)&Bhs[(j << 4) + c][g8];
      sx8 bl = *(const sx8*)&Bls[(j << 4) + c][g8];
      acc[j] = __builtin_amdgcn_mfma_f32_16x16x32_bf16(ah, bh, acc[j], 0, 0, 0);
      acc[j] = __builtin_amdgcn_mfma_f32_16x16x32_bf16(al, bh, acc[j], 0, 0, 0);
      acc[j] = __builtin_amdgcn_mfma_f32_16x16x32_bf16(ah, bl, acc[j], 0, 0, 0);
    }
    __syncthreads();
  }

  const int orow = bm + (w << 4) + (g << 2);
#pragma unroll
  for (int j = 0; j < 16; ++j) {
    const int col = (j << 4) + c;
    const float bb = bias[col];
    if constexpr (EP == 0) {
#pragma unroll
      for (int i = 0; i < 4; ++i)
        C[(size_t)(orow + i) * 256 + col] = acc[j][i] + bb;
    } else {  // EP == 3: q bf16 prescaled head-major
      const int h = col >> 5, d = col & 31;
#pragma unroll
      for (int i = 0; i < 4; ++i) {
        int r = orow + i;
        qout[((size_t)(((r >> 12) << 3) + h) * 4096 + (r & 4095)) * 32 + d]
            = f2bf((acc[j][i] + bb) * QSCALE);
      }
    }
  }
}

// ---------- classic split-bf16 GEMM (f32 A): conv partials + kv ----------
template<bool GATHER, int EPI>
__global__ __launch_bounds__(256) void gemm_split_kernel(
    const float* __restrict__ A, const short* __restrict__ Bth,
    const short* __restrict__ Btl, const float* __restrict__ bias,
    float* __restrict__ C, short* __restrict__ kout, short* __restrict__ vout,
    int M, int N, int K)
{
  __shared__ short Ah[64][40], Al[64][40], Bh[64][40], Bl[64][40];
  const int t = threadIdx.x;
  const int bm = blockIdx.y << 6, bn = blockIdx.x << 6;
  const int ar = t >> 2, ak = (t & 3) << 3;
  const int bc = t >> 2, bk = (t & 3) << 3;

  int sp_base = 0;
  if (GATHER) {
    int gr = bm + ar;
    int b = gr >> 8, mm2 = gr & 255;
    int oh = mm2 >> 4, ow = mm2 & 15;
    sp_base = b * 4096 + oh * 256 + ow * 4;
  }
  const size_t brow = (size_t)(bn + bc) * K;

  const int KS = K / gridDim.z;
  const int kbeg = blockIdx.z * KS, kend = kbeg + KS;

  float4 pa0, pa1; sx8 pbh, pbl;
  auto LOADG = [&](int k0) {
    int k = k0 + ak;
    const float* ap;
    if (GATHER) {
      int pos = k >> 8, ci = k & 255;
      ap = &A[(size_t)(sp_base + ((pos >> 2) << 6) + (pos & 3)) * 256 + ci];
    } else {
      ap = &A[(size_t)(bm + ar) * K + k];
    }
    pa0 = *(const float4*)ap;
    pa1 = *(const float4*)(ap + 4);
    pbh = *(const sx8*)&Bth[brow + k0 + bk];
    pbl = *(const sx8*)&Btl[brow + k0 + bk];
  };

  const int w = t >> 6, l = t & 63, g = l >> 4, c = l & 15;
  const int wr = w >> 1, wc = w & 1;
  const int ra0 = (wr << 5) + c, ra1 = ra0 + 16;
  const int cb0 = (wc << 5) + c, cb1 = cb0 + 16;
  const int g8 = g << 3;

  fx4 acc00 = {0.f,0.f,0.f,0.f}, acc01 = acc00, acc10 = acc00, acc11 = acc00;

  LOADG(kbeg);
  for (int k0 = kbeg; k0 < kend; k0 += 32) {
    sx4 AH0, AL0, AH1, AL1;
    AH0[0]=f2bf(pa0.x); AL0[0]=f2bf(pa0.x-bf2f(AH0[0]));
    AH0[1]=f2bf(pa0.y); AL0[1]=f2bf(pa0.y-bf2f(AH0[1]));
    AH0[2]=f2bf(pa0.z); AL0[2]=f2bf(pa0.z-bf2f(AH0[2]));
    AH0[3]=f2bf(pa0.w); AL0[3]=f2bf(pa0.w-bf2f(AH0[3]));
    AH1[0]=f2bf(pa1.x); AL1[0]=f2bf(pa1.x-bf2f(AH1[0]));
    AH1[1]=f2bf(pa1.y); AL1[1]=f2bf(pa1.y-bf2f(AH1[1]));
    AH1[2]=f2bf(pa1.z); AL1[2]=f2bf(pa1.z-bf2f(AH1[2]));
    AH1[3]=f2bf(pa1.w); AL1[3]=f2bf(pa1.w-bf2f(AH1[3]));
    *(sx4*)&Ah[ar][ak]     = AH0;  *(sx4*)&Ah[ar][ak + 4] = AH1;
    *(sx4*)&Al[ar][ak]     = AL0;  *(sx4*)&Al[ar][ak + 4] = AL1;
    *(sx8*)&Bh[bc][bk] = pbh;      *(sx8*)&Bl[bc][bk] = pbl;
    __syncthreads();
    if (k0 + 32 < kend) LOADG(k0 + 32);

    sx8 a0h = *(const sx8*)&Ah[ra0][g8];
    sx8 a0l = *(const sx8*)&Al[ra0][g8];
    sx8 a1h = *(const sx8*)&Ah[ra1][g8];
    sx8 a1l = *(const sx8*)&Al[ra1][g8];
    sx8 b0h = *(const sx8*)&Bh[cb0][g8];
    sx8 b0l = *(const sx8*)&Bl[cb0][g8];
    sx8 b1h = *(const sx8*)&Bh[cb1][g8];
    sx8 b1l = *(const sx8*)&Bl[cb1][g8];

    acc00 = __builtin_amdgcn_mfma_f32_16x16x32_bf16(a0h, b0h, acc00, 0, 0, 0);
    acc01 = __builtin_amdgcn_mfma_f32_16x16x32_bf16(a0h, b1h, acc01, 0, 0, 0);
    acc10 = __builtin_amdgcn_mfma_f32_16x16x32_bf16(a1h, b0h, acc10, 0, 0, 0);
    acc11 = __builtin_amdgcn_mfma_f32_16x16x32_bf16(a1h, b1h, acc11, 0, 0, 0);
    acc00 = __builtin_amdgcn_mfma_f32_16x16x32_bf16(a0l, b0h, acc00, 0, 0, 0);
    acc01 = __builtin_amdgcn_mfma_f32_16x16x32_bf16(a0l, b1h, acc01, 0, 0, 0);
    acc10 = __builtin_amdgcn_mfma_f32_16x16x32_bf16(a1l, b0h, acc10, 0, 0, 0);
    acc11 = __builtin_amdgcn_mfma_f32_16x16x32_bf16(a1l, b1h, acc11, 0, 0, 0);
    acc00 = __builtin_amdgcn_mfma_f32_16x16x32_bf16(a0h, b0l, acc00, 0, 0, 0);
    acc01 = __builtin_amdgcn_mfma_f32_16x16x32_bf16(a0h, b1l, acc01, 0, 0, 0);
    acc10 = __builtin_amdgcn_mfma_f32_16x16x32_bf16(a1h, b0l, acc10, 0, 0, 0);
    acc11 = __builtin_amdgcn_mfma_f32_16x16x32_bf16(a1h, b1l, acc11, 0, 0, 0);
    __syncthreads();
  }

  const int col0 = bn + (wc << 5);
  const int row0 = bm + (wr << 5) + (g << 2);
  if constexpr (EPI == 1) {
    float* Cz = C + (size_t)blockIdx.z * M * N;
#pragma unroll
    for (int i = 0; i < 4; ++i) {
      Cz[(size_t)(row0 + i) * N + col0 + c]           = acc00[i];
      Cz[(size_t)(row0 + i) * N + col0 + 16 + c]      = acc01[i];
      Cz[(size_t)(row0 + 16 + i) * N + col0 + c]      = acc10[i];
      Cz[(size_t)(row0 + 16 + i) * N + col0 + 16 + c] = acc11[i];
    }
  } else {  // EPI == 2: kv emit -> K/V [b*8+h][m][32] bf16
    const float b0 = bias[col0 + c], b1 = bias[col0 + 16 + c];
    auto emit = [&](int row, int n, float v) {
      int b = row >> 8, m = row & 255;
      short* dst = (n < 256) ? kout : vout;
      int nn = n & 255;
      int h = nn >> 5, d = nn & 31;
      dst[(size_t)(((b << 3) + h) * 256 + m) * 32 + d] = f2bf(v);
    };
#pragma unroll
    for (int i = 0; i < 4; ++i) {
      emit(row0 + i,      col0 + c,      acc00[i] + b0);
      emit(row0 + i,      col0 + 16 + c, acc01[i] + b1);
      emit(row0 + 16 + i, col0 + c,      acc10[i] + b0);
      emit(row0 + 16 + i, col0 + 16 + c, acc11[i] + b1);
    }
  }
}

// -------- fused K-split reduce (8 parts) + bias + LayerNorm: xs row per block --------
__global__ __launch_bounds__(256) void ln_reduce_kernel(
    const float* __restrict__ parts, const float* __restrict__ bias,
    const float* __restrict__ g, const float* __restrict__ bta,
    float* __restrict__ xs)
{
  const int row = blockIdx.x, t = threadIdx.x;
  const size_t MN = (size_t)4096 * 256;
  const size_t off = (size_t)row * CC + t;
  float v = bias[t];
#pragma unroll
  for (int p = 0; p < 8; ++p) v += parts[p * MN + off];
  float s = v, s2 = v * v;
#pragma unroll
  for (int offs = 32; offs; offs >>= 1) {
    s  += __shfl_xor(s,  offs, 64);
    s2 += __shfl_xor(s2, offs, 64);
  }
  __shared__ float red[8];
  const int w = t >> 6, lane = t & 63;
  if (lane == 0) { red[w] = s; red[4 + w] = s2; }
  __syncthreads();
  float ts  = red[0] + red[1] + red[2] + red[3];
  float ts2 = red[4] + red[5] + red[6] + red[7];
  float mu  = ts * (1.0f / 256.0f);
  float var = ts2 * (1.0f / 256.0f) - mu * mu;
  float o = (v - mu) * rsqrtf(var + 1e-6f) * g[t] + bta[t];
  xs[off] = o;
}

// ------- MFMA attention v8: no-max softmax (exp2 direct), row-sum via ones-MFMA -------
// Same data flow as v4; max-pass and shuffle-sum deleted. Denominator accumulated
// on the idle MFMA pipe: o2 = mfma(P_frag, ones, o2) -> o2[i] = rowsum, per-lane.
__global__ __launch_bounds__(256, 3) void attn_mfma8_kernel(
    short* __restrict__ qob, short* __restrict__ olo,
    const short* __restrict__ kbf, const short* __restrict__ vbf)
{
  __shared__ short Vt[32 * 264];       // V^T [d][m'], stride 264
  __shared__ short Ps[4 * 16 * 264];   // per-wave P [16 rows][m'], stride 264

  const int tid = threadIdx.x;
  const int bid = blockIdx.x;
  const int nt = bid & 63, h = (bid >> 6) & 7, b = bid >> 9;
  const int n0 = nt << 6;
  const int bh = (b << 3) + h;
  const short* kb = kbf + (size_t)bh * 8192;
  const short* vb = vbf + (size_t)bh * 8192;

  // ---- stage V^T with m-permute ----
  {
    const int msrc = ((tid & 15) << 4) | (tid >> 4);
    sx8 v0 = *(const sx8*)&vb[msrc * 32 + 0];
    sx8 v1 = *(const sx8*)&vb[msrc * 32 + 8];
    sx8 v2 = *(const sx8*)&vb[msrc * 32 + 16];
    sx8 v3 = *(const sx8*)&vb[msrc * 32 + 24];
#pragma unroll
    for (int e = 0; e < 8; ++e) {
      Vt[(e)      * 264 + tid] = v0[e];
      Vt[(8 + e)  * 264 + tid] = v1[e];
      Vt[(16 + e) * 264 + tid] = v2[e];
      Vt[(24 + e) * 264 + tid] = v3[e];
    }
  }

  const int w = tid >> 6, l = tid & 63;
  const int g = l >> 4, c = l & 15;

  // ---- Q A-fragment: direct bf16 load ----
  sx8 aq = *(const sx8*)&qob[((size_t)bh * 4096 + n0 + w * 16 + c) * 32 + (g << 3)];

  // ---- S = Q K^T ----
  fx4 acc[16];
#pragma unroll
  for (int j = 0; j < 16; ++j) {
    sx8 bk = *(const sx8*)&kb[(j * 16 + c) * 32 + (g << 3)];
    fx4 z = {0.f, 0.f, 0.f, 0.f};
    acc[j] = __builtin_amdgcn_mfma_f32_16x16x32_bf16(aq, bk, z, 0, 0, 0);
  }

  // ---- no-max softmax numerator: P = exp2(S) (|S| small; exact after normalize) ----
#pragma unroll
  for (int j = 0; j < 16; ++j) {
#pragma unroll
    for (int i = 0; i < 4; ++i) acc[j][i] = fexp2(acc[j][i]);
  }

  // ---- P -> LDS: contiguous per thread; 8 cvt_pk + 2 b128 per row ----
  const int pbase = (w << 4) * 264;
#pragma unroll
  for (int i = 0; i < 4; ++i) {
    unsigned p0 = cvtpk_bf16(acc[0][i],  acc[1][i]);
    unsigned p1 = cvtpk_bf16(acc[2][i],  acc[3][i]);
    unsigned p2 = cvtpk_bf16(acc[4][i],  acc[5][i]);
    unsigned p3 = cvtpk_bf16(acc[6][i],  acc[7][i]);
    unsigned p4 = cvtpk_bf16(acc[8][i],  acc[9][i]);
    unsigned p5 = cvtpk_bf16(acc[10][i], acc[11][i]);
    unsigned p6 = cvtpk_bf16(acc[12][i], acc[13][i]);
    unsigned p7 = cvtpk_bf16(acc[14][i], acc[15][i]);
    unsigned* dst = (unsigned*)&Ps[pbase + ((g << 2) + i) * 264 + (c << 4)];
    uint4 lo4; lo4.x = p0; lo4.y = p1; lo4.z = p2; lo4.w = p3;
    uint4 hi4; hi4.x = p4; hi4.y = p5; hi4.z = p6; hi4.w = p7;
    *(uint4*)dst       = lo4;
    *(uint4*)(dst + 4) = hi4;
  }

  __syncthreads();

  // ---- O = P V and rowsum = P @ ones, both on the matrix pipe ----
  const short onebf = (short)0x3F80;   // bf16 1.0
  sx8 ones = { onebf, onebf, onebf, onebf, onebf, onebf, onebf, onebf };
  fx4 o0 = {0.f,0.f,0.f,0.f}, o1 = o0, o2 = o0;
#pragma unroll
  for (int s = 0; s < 8; ++s) {
    sx8 ap  = *(const sx8*)&Ps[pbase + c * 264 + (s << 5) + (g << 3)];
    sx8 bv0 = *(const sx8*)&Vt[(c)      * 264 + (s << 5) + (g << 3)];
    sx8 bv1 = *(const sx8*)&Vt[(16 + c) * 264 + (s << 5) + (g << 3)];
    o0 = __builtin_amdgcn_mfma_f32_16x16x32_bf16(ap, bv0, o0, 0, 0, 0);
    o1 = __builtin_amdgcn_mfma_f32_16x16x32_bf16(ap, bv1, o1, 0, 0, 0);
    o2 = __builtin_amdgcn_mfma_f32_16x16x32_bf16(ap, ones, o2, 0, 0, 0);
  }

  // ---- normalize (denominator from o2), split to bf16 hi/lo, write [b*8+h][n][32] ----
#pragma unroll
  for (int i = 0; i < 4; ++i) {
    float inv = frcp(o2[i]);
    int n = n0 + w * 16 + (g << 2) + i;
    size_t base = ((size_t)bh * 4096 + n) * 32;
    float v0 = o0[i] * inv, v1 = o1[i] * inv;
    short h0 = f2bf(v0), h1 = f2bf(v1);
    qob[base + c]      = h0;  olo[base + c]      = f2bf(v0 - bf2f(h0));
    qob[base + 16 + c] = h1;  olo[base + 16 + c] = f2bf(v1 - bf2f(h1));
  }
}

extern "C" void kernel_launch(void* const* d_in, const int* in_sizes, int n_in,
                              void* d_out, int out_size, void* d_ws, size_t ws_size,
                              hipStream_t stream) {
  const float* x      = (const float*)d_in[0];
  const float* q_w    = (const float*)d_in[1];
  const float* q_b    = (const float*)d_in[2];
  const float* kv_w   = (const float*)d_in[3];
  const float* kv_b   = (const float*)d_in[4];
  const float* sr_w   = (const float*)d_in[5];
  const float* sr_b   = (const float*)d_in[6];
  const float* norm_g = (const float*)d_in[7];
  const float* norm_b = (const float*)d_in[8];
  const float* proj_w = (const float*)d_in[9];
  const float* proj_b = (const float*)d_in[10];
  float* out = (float*)d_out;

  // workspace
  float* xsbuf = (float*)d_ws;                     // 4 MB
  short* qbf   = (short*)(xsbuf + 1048576);        // 32 MB: q bf16, then O-hi
  short* olo   = qbf + 16777216;                   // 32 MB: O-lo
  short* kbf   = olo + 16777216;                   // 4 MB
  short* vbf   = kbf + 2097152;                    // 4 MB
  short* qwt_h  = vbf + 2097152;
  short* qwt_l  = qwt_h + 65536;
  short* kvwt_h = qwt_l + 65536;
  short* kvwt_l = kvwt_h + 131072;
  short* pwt_h  = kvwt_l + 131072;
  short* pwt_l  = pwt_h + 65536;
  short* swt_h  = pwt_l + 65536;
  short* swt_l  = swt_h + 1048576;
  // d_out (64 MB) as early scratch: conv K-split partials (8 x 4 MB = 32 MB)
  float* partf = out;

  dim3 blk(256);

  wsplit_kernel<true><<<dim3(CC/64, CC/64), blk, 0, stream>>>(q_w, qwt_h, qwt_l, CC, CC);
  wsplit_kernel<false><<<dim3(2*CC/64, CC/64), blk, 0, stream>>>(kv_w, kvwt_h, kvwt_l, CC, 2*CC);
  wsplit_kernel<true><<<dim3(CC/64, CC/64), blk, 0, stream>>>(proj_w, pwt_h, pwt_l, CC, CC);
  wsplit_kernel<false><<<dim3(CC/64, 4096/64), blk, 0, stream>>>(sr_w, swt_h, swt_l, 4096, CC);

  // 1) q = x @ q_w + q_b -> bf16 prescaled [b*8+h][n][32]
  gemm_wide_kernel<0,3><<<dim3((B_*NN)/64), blk, 0, stream>>>(
      x, nullptr, qwt_h, qwt_l, q_b, nullptr, qbf, B_*NN, CC);

  // 2) conv (gathered GEMM, K=4096), K-split x8 -> f32 partials in d_out
  gemm_split_kernel<true,1><<<dim3(CC/64, (B_*MM)/64, 8), blk, 0, stream>>>(
      x, swt_h, swt_l, sr_b, partf, nullptr, nullptr, B_*MM, CC, 4096);

  // 3) fused reduce (8 parts) + bias + LayerNorm
  ln_reduce_kernel<<<B_ * MM, blk, 0, stream>>>(partf, sr_b, norm_g, norm_b, xsbuf);

  // 4) kv = xs @ kv_w + kv_b -> bf16 K/V [b*8+h][m][32]
  gemm_split_kernel<false,2><<<dim3((2*CC)/64, (B_*MM)/64, 1), blk, 0, stream>>>(
      xsbuf, kvwt_h, kvwt_l, kv_b, nullptr, kbf, vbf, B_*MM, 2*CC, CC);

  // 5) attention: reads qbf, writes O-hi over qbf + O-lo
  attn_mfma8_kernel<<<B_ * NH * (NN / 64), blk, 0, stream>>>(qbf, olo, kbf, vbf);

  // 6) out = O @ proj_w + proj_b
  gemm_wide_kernel<2,0><<<dim3((B_*NN)/64), blk, 0, stream>>>(
      qbf, olo, pwt_h, pwt_l, proj_b, out, nullptr, B_*NN, CC);
}